// Round 5
// baseline (93.232 us; speedup 1.0000x reference)
//
#include <hip/hip_runtime.h>
#include <stdint.h>

typedef uint32_t u32;
typedef unsigned short u16;

#define LDT 40  // GEMM LDS row stride (elements)

typedef __bf16 bf16x8 __attribute__((ext_vector_type(8)));
typedef float  f32x4  __attribute__((ext_vector_type(4)));

__device__ __forceinline__ float bf2f(u16 x) {
  union { float f; u32 u; } c; c.u = ((u32)x) << 16; return c.f;
}
__device__ __forceinline__ u16 f2bf(float f) {
  union { float f; u32 u; } c; c.f = f;
  u32 b = c.u;
  return (u16)((b + 0x7FFFu + ((b >> 16) & 1u)) >> 16);
}
__device__ __forceinline__ u32 pk2(float lo, float hi) {
  return (u32)f2bf(lo) | ((u32)f2bf(hi) << 16);
}

// ---------------------------------------------------------------------------
// Kernel 0: transpose+cast Wq/Wk/Wv (f32 [256][256] -> bf16 WT [n][k])
// ---------------------------------------------------------------------------
__global__ __launch_bounds__(256) void prep_transpose(
    const float* __restrict__ Wq, const float* __restrict__ Wk, const float* __restrict__ Wv,
    u16* __restrict__ WTq, u16* __restrict__ WTk, u16* __restrict__ WTv)
{
  int z = blockIdx.z, bx = blockIdx.x, by = blockIdx.y;
  int x = threadIdx.x, y = threadIdx.y;  // 32 x 8
  __shared__ u16 tile[32][33];
  const float* W  = (z == 0) ? Wq : (z == 1) ? Wk : Wv;
  u16*         WT = (z == 0) ? WTq : (z == 1) ? WTk : WTv;
  for (int yy = y; yy < 32; yy += 8)
    tile[yy][x] = f2bf(W[(size_t)(by * 32 + yy) * 256 + bx * 32 + x]);
  __syncthreads();
  for (int yy = y; yy < 32; yy += 8)
    WT[(size_t)(bx * 32 + yy) * 256 + by * 32 + x] = tile[x][yy];
}

// ---------------------------------------------------------------------------
// Kernel 0a: Wg2^T bf16 padded [32 j][40 i]; zeros outside 24x24.
// wg2bf[j*40+i] = Wg2[i][j]
// ---------------------------------------------------------------------------
__global__ __launch_bounds__(256) void prep_wg2(
    const float* __restrict__ Wg2, u16* __restrict__ wg2bf)
{
  int t = threadIdx.x;
  for (int i = t; i < 1280; i += 256) {
    int j = i / 40, k = i % 40;
    float v = (j < 24 && k < 24) ? Wg2[(size_t)k * 24 + j] : 0.f;
    wg2bf[i] = f2bf(v);
  }
}

// ---------------------------------------------------------------------------
// Kernel 0b: combined weights CT[z][c][k] = (W{q,k} @ Wg1)^T  (bf16, c<24),
//            bcomb[z][c] = b{q,k}@Wg1 (+ -bg1 for z=0)
// ---------------------------------------------------------------------------
__global__ __launch_bounds__(256) void prep_comb(
    const u16* __restrict__ WTq, const u16* __restrict__ WTk,
    const float* __restrict__ Wg1, const float* __restrict__ bg1,
    const float* __restrict__ bq, const float* __restrict__ bk,
    u16* __restrict__ CT, float* __restrict__ bcomb)
{
  int c = blockIdx.x, z = blockIdx.y;
  int t = threadIdx.x;
  const u16*   WT = (z == 0) ? WTq : WTk;
  const float* b  = (z == 0) ? bq : bk;

  float acc = 0.f;
#pragma unroll 8
  for (int e = 0; e < 256; e++)
    acc += bf2f(WT[(size_t)e * 256 + t]) * Wg1[(size_t)e * 24 + c];
  CT[(size_t)z * 8192 + (size_t)c * 256 + t] = f2bf(acc);

  __shared__ float red[256];
  red[t] = b[t] * Wg1[(size_t)t * 24 + c];
  __syncthreads();
  for (int s = 128; s > 0; s >>= 1) {
    if (t < s) red[t] += red[t + s];
    __syncthreads();
  }
  if (t == 0)
    bcomb[z * 24 + c] = red[0] - ((z == 0) ? bg1[c] : 0.f);
}

// ---------------------------------------------------------------------------
// Kernel 1: projections. blockIdx.x<2: Y[8192,256]=X@W+b (bf16 out).
// blockIdx.x==2: extra 24 cols via combined weights -> qadj/kg1 (f32, stride 32).
// ---------------------------------------------------------------------------
__global__ __launch_bounds__(256) void gemm_qkv(
    const float* __restrict__ Xq, const float* __restrict__ Xk, const float* __restrict__ Xv,
    const u16* __restrict__ WTq, const u16* __restrict__ WTk, const u16* __restrict__ WTv,
    const float* __restrict__ bq, const float* __restrict__ bk, const float* __restrict__ bv,
    const u16* __restrict__ CT, const float* __restrict__ bcomb,
    u16* __restrict__ Oq, u16* __restrict__ Ok, u16* __restrict__ Ov,
    float* __restrict__ qadj, float* __restrict__ kg1)
{
  int z = blockIdx.z;
  int nblk = blockIdx.x;
  if (nblk == 2 && z == 2) return;

  const float* X = (z == 0) ? Xq : (z == 1) ? Xk : Xv;
  int m0 = blockIdx.y * 128;
  int t = threadIdx.x;
  int lane = t & 63, wid = t >> 6;
  int fr = lane & 15, fg = lane >> 4;
  int sr = t >> 1;
  int sc = (t & 1) * 16;

  __shared__ __align__(16) u16 la[128 * LDT];
  __shared__ __align__(16) u16 lb[128 * LDT];

  if (nblk < 2) {
    const u16*   WT   = (z == 0) ? WTq : (z == 1) ? WTk : WTv;
    const float* bias = (z == 0) ? bq : (z == 1) ? bk : bv;
    u16*         O    = (z == 0) ? Oq : (z == 1) ? Ok : Ov;
    int n0 = nblk * 128;
    int wr = wid >> 1, wc = wid & 1;

    f32x4 acc[4][4];
#pragma unroll
    for (int i = 0; i < 4; i++)
#pragma unroll
      for (int j = 0; j < 4; j++) acc[i][j] = (f32x4){0.f, 0.f, 0.f, 0.f};

    for (int kt = 0; kt < 256; kt += 32) {
      const float4* ga = (const float4*)(X + (size_t)(m0 + sr) * 256 + kt + sc);
      float4 a0 = ga[0], a1 = ga[1], a2 = ga[2], a3 = ga[3];
      const uint4* gb = (const uint4*)(WT + (size_t)(n0 + sr) * 256 + kt + sc);
      uint4 b0 = gb[0], b1 = gb[1];

      uint4 wa0, wa1;
      wa0.x = pk2(a0.x, a0.y); wa0.y = pk2(a0.z, a0.w);
      wa0.z = pk2(a1.x, a1.y); wa0.w = pk2(a1.z, a1.w);
      wa1.x = pk2(a2.x, a2.y); wa1.y = pk2(a2.z, a2.w);
      wa1.z = pk2(a3.x, a3.y); wa1.w = pk2(a3.z, a3.w);

      __syncthreads();
      *(uint4*)&la[sr * LDT + sc]     = wa0;
      *(uint4*)&la[sr * LDT + sc + 8] = wa1;
      *(uint4*)&lb[sr * LDT + sc]     = b0;
      *(uint4*)&lb[sr * LDT + sc + 8] = b1;
      __syncthreads();

      bf16x8 af[4], bfr[4];
#pragma unroll
      for (int s = 0; s < 4; s++)
        af[s] = *(const bf16x8*)&la[(wr * 64 + s * 16 + fr) * LDT + fg * 8];
#pragma unroll
      for (int s = 0; s < 4; s++)
        bfr[s] = *(const bf16x8*)&lb[(wc * 64 + s * 16 + fr) * LDT + fg * 8];
#pragma unroll
      for (int i = 0; i < 4; i++)
#pragma unroll
        for (int j = 0; j < 4; j++)
          acc[i][j] = __builtin_amdgcn_mfma_f32_16x16x32_bf16(af[i], bfr[j], acc[i][j], 0, 0, 0);
    }

#pragma unroll
    for (int i = 0; i < 4; i++) {
      int rowb = m0 + wr * 64 + i * 16 + fg * 4;
#pragma unroll
      for (int j = 0; j < 4; j++) {
        int col = n0 + wc * 64 + j * 16 + fr;
        float bb = bias[col];
#pragma unroll
        for (int r = 0; r < 4; r++)
          O[(size_t)(rowb + r) * 256 + col] = f2bf(acc[i][j][r] + bb);
      }
    }
  } else {
    const u16*   BT = CT + (size_t)z * 8192;
    const float* bc = bcomb + z * 24;
    float*       O  = (z == 0) ? qadj : kg1;

    f32x4 acc[2][2];
#pragma unroll
    for (int i = 0; i < 2; i++)
#pragma unroll
      for (int j = 0; j < 2; j++) acc[i][j] = (f32x4){0.f, 0.f, 0.f, 0.f};

    for (int kt = 0; kt < 256; kt += 32) {
      const float4* ga = (const float4*)(X + (size_t)(m0 + sr) * 256 + kt + sc);
      float4 a0 = ga[0], a1 = ga[1], a2 = ga[2], a3 = ga[3];
      uint4 b0, b1;
      if (t < 64) {
        const uint4* gb = (const uint4*)(BT + (size_t)sr * 256 + kt + sc);
        b0 = gb[0]; b1 = gb[1];
      }
      uint4 wa0, wa1;
      wa0.x = pk2(a0.x, a0.y); wa0.y = pk2(a0.z, a0.w);
      wa0.z = pk2(a1.x, a1.y); wa0.w = pk2(a1.z, a1.w);
      wa1.x = pk2(a2.x, a2.y); wa1.y = pk2(a2.z, a2.w);
      wa1.z = pk2(a3.x, a3.y); wa1.w = pk2(a3.z, a3.w);

      __syncthreads();
      *(uint4*)&la[sr * LDT + sc]     = wa0;
      *(uint4*)&la[sr * LDT + sc + 8] = wa1;
      if (t < 64) {
        *(uint4*)&lb[sr * LDT + sc]     = b0;
        *(uint4*)&lb[sr * LDT + sc + 8] = b1;
      }
      __syncthreads();

      bf16x8 af[2], bfr[2];
#pragma unroll
      for (int s = 0; s < 2; s++)
        af[s] = *(const bf16x8*)&la[(wid * 32 + s * 16 + fr) * LDT + fg * 8];
#pragma unroll
      for (int s = 0; s < 2; s++)
        bfr[s] = *(const bf16x8*)&lb[(s * 16 + fr) * LDT + fg * 8];
#pragma unroll
      for (int i = 0; i < 2; i++)
#pragma unroll
        for (int j = 0; j < 2; j++)
          acc[i][j] = __builtin_amdgcn_mfma_f32_16x16x32_bf16(af[i], bfr[j], acc[i][j], 0, 0, 0);
    }

#pragma unroll
    for (int i = 0; i < 2; i++) {
      int rowb = m0 + wid * 32 + i * 16 + fg * 4;
#pragma unroll
      for (int j = 0; j < 2; j++) {
        int col = j * 16 + fr;
        if (col < 24) {
#pragma unroll
          for (int r = 0; r < 4; r++)
            O[(size_t)(rowb + r) * 32 + col] = acc[i][j][r] + bc[col];
        }
      }
    }
  }
}

// ---------------------------------------------------------------------------
// Kernel 2: fused edge/attention, MFMA for dot, MLP and PV.
// One 256-thread block (4 waves) per point.
// ---------------------------------------------------------------------------
__global__ __launch_bounds__(256) void edge_attn(
    const u16* __restrict__ qb, const u16* __restrict__ kb, const u16* __restrict__ vb,
    const float* __restrict__ kg1g, const float* __restrict__ qadjg,
    const int* __restrict__ ip, const float* __restrict__ raw,
    const float* __restrict__ rpe, const u16* __restrict__ wg2bf,
    const float* __restrict__ bg2g, float* __restrict__ out)
{
  int p = blockIdx.x, t = threadIdx.x;
  int lane = t & 63, w = t >> 6;
  int fr = lane & 15, fg = lane >> 4;

  __shared__ __align__(16) u16   kv_s[32 * 264];   // K_g [32][264], later V_g [32][260]
  __shared__ __align__(16) u16   qbd_s[16 * 264];  // block-diag Q^T (bf16)
  __shared__ __align__(16) u16   wg2_s[32 * 40];   // Wg2^T padded
  __shared__ __align__(16) u16   attb_s[16 * 40];  // e-values bf16 [h][n]
  __shared__ __align__(16) float kg1_s[32 * 32];
  __shared__ float qadj_s[24];
  __shared__ float g_s[32 * 33];
  __shared__ float sh_s[32 * 3];
  __shared__ float is_s[8];
  __shared__ int   idx_s[32];
  __shared__ float bg2_s[24];

  // ---- Phase A: point-local staging (no gathers yet)
  if (t < 32) idx_s[t] = ip[(size_t)p * 32 + t];
  else if (t < 56) bg2_s[t - 32] = bg2g[t - 32];
  else if (t >= 64 && t < 88) qadj_s[t - 64] = qadjg[(size_t)p * 32 + (t - 64)];
  if (t >= 96) {
    int i = t - 96;  // 0..159 -> 160 uint4 = 2560B
    *(uint4*)&wg2_s[i * 8] = ((const uint4*)wg2bf)[i];
  }
  {
    int row = t >> 4, c0 = (t & 15) * 16;
    uint4 v0 = {0, 0, 0, 0}, v1 = {0, 0, 0, 0};
    if ((c0 >> 5) == row) {
      const uint4* qp = (const uint4*)(qb + (size_t)p * 256 + c0);
      v0 = qp[0]; v1 = qp[1];
    }
    *(uint4*)&qbd_s[row * 264 + c0]     = v0;
    *(uint4*)&qbd_s[row * 264 + c0 + 8] = v1;
  }
  if (t < 32) {
    float x  = rpe[(size_t)p * 96 + t * 3 + 0];
    float y  = rpe[(size_t)p * 96 + t * 3 + 1];
    float z  = rpe[(size_t)p * 96 + t * 3 + 2];
    float rl = sqrtf(x * x + y * y + z * z);
    float inv = 1.f / fmaxf(rl, 1e-12f);
    float tt2 = fminf(fmaxf((rl - 0.001f) * 250.f, 0.f), 1.f);
    float cut = 0.5f * (1.f - cosf(tt2 * 3.14159265358979f));
    float s3c = 1.7320508075688772f * inv * cut;
    sh_s[t * 3 + 0] = x * s3c; sh_s[t * 3 + 1] = y * s3c; sh_s[t * 3 + 2] = z * s3c;
  }
  __syncthreads();

  // ---- Phase B: gather K rows + kg1 rows (coalesced)
  {
    int n = t >> 3, c0 = (t & 7) * 32;
    const uint4* kp = (const uint4*)(kb + (size_t)idx_s[n] * 256 + c0);
    uint4 k0 = kp[0], k1 = kp[1], k2 = kp[2], k3 = kp[3];
    u16* d = &kv_s[n * 264 + c0];
    *(uint4*)(d)      = k0; *(uint4*)(d + 8)  = k1;
    *(uint4*)(d + 16) = k2; *(uint4*)(d + 24) = k3;
    *(float4*)&kg1_s[n * 32 + (t & 7) * 4] =
        *(const float4*)(kg1g + (size_t)idx_s[n] * 32 + (t & 7) * 4);
  }
  __syncthreads();

  // ---- Phase D: waves 0,1 dot MFMA; waves 2,3 MLP MFMA
  f32x4 dacc = {0.f, 0.f, 0.f, 0.f};
  if (w < 2) {
    const u16* arow = &kv_s[(w * 16 + fr) * 264];
    const u16* brow = &qbd_s[fr * 264];
#pragma unroll
    for (int ks = 0; ks < 8; ks++) {
      bf16x8 a = *(const bf16x8*)(arow + ks * 32 + fg * 8);
      bf16x8 b = *(const bf16x8*)(brow + ks * 32 + fg * 8);
      dacc = __builtin_amdgcn_mfma_f32_16x16x32_bf16(a, b, dacc, 0, 0, 0);
    }
  } else {
    int mt = w - 2;
    bf16x8 a;
    if (fg < 3) {
      int rowb = (mt * 16 + fr) * 32 + fg * 8;
      int kq = fg * 8;
#pragma unroll
      for (int j = 0; j < 8; j++) {
        float x = fmaxf(kg1_s[rowb + j] - qadj_s[kq + j], 0.f);
        a[j] = (__bf16)x;
      }
    } else {
#pragma unroll
      for (int j = 0; j < 8; j++) a[j] = (__bf16)0.f;
    }
    bf16x8 b0 = *(const bf16x8*)&wg2_s[fr * 40 + fg * 8];
    bf16x8 b1 = *(const bf16x8*)&wg2_s[(16 + fr) * 40 + fg * 8];
    f32x4 g0 = {0.f, 0.f, 0.f, 0.f}, g1 = {0.f, 0.f, 0.f, 0.f};
    g0 = __builtin_amdgcn_mfma_f32_16x16x32_bf16(a, b0, g0, 0, 0, 0);
    g1 = __builtin_amdgcn_mfma_f32_16x16x32_bf16(a, b1, g1, 0, 0, 0);
    int e0 = mt * 16 + fg * 4;
    float bb0 = bg2_s[fr];
    float bb1 = (fr < 8) ? bg2_s[16 + fr] : 0.f;
#pragma unroll
    for (int r = 0; r < 4; r++) {
      g_s[(e0 + r) * 33 + fr]      = g0[r] + bb0;
      g_s[(e0 + r) * 33 + 16 + fr] = g1[r] + bb1;
    }
  }
  __syncthreads();

  // ---- Phase E: waves 0,1 logits+exp -> attb; waves 2,3 gather V rows
  if (w < 2) {
    if (fr < 8) {
#pragma unroll
      for (int r = 0; r < 4; r++) {
        int n = w * 16 + fg * 4 + r;
        float pos = g_s[n * 33 + fr * 3 + 0] * sh_s[n * 3 + 0]
                  + g_s[n * 33 + fr * 3 + 1] * sh_s[n * 3 + 1]
                  + g_s[n * 33 + fr * 3 + 2] * sh_s[n * 3 + 2];
        float rw = raw[(size_t)p * 256 + n * 8 + fr];
        float ev = __expf((dacc[r] + pos + rw) * 0.17677669529663687f);
        attb_s[fr * 40 + n] = f2bf(ev);
      }
    }
  } else {
    int tt = t - 128;           // 0..127
    int n = tt >> 2, c0 = (tt & 3) * 64;
    const uint2* vp = (const uint2*)(vb + (size_t)idx_s[n] * 256 + c0);
    u16* d = &kv_s[n * 260 + c0];
#pragma unroll
    for (int jj = 0; jj < 16; jj++) *(uint2*)(d + jj * 4) = vp[jj];
  }
  __syncthreads();

  // ---- Phase F: softmax denominators (wave 0, shfl-reduce, no extra barrier)
  if (w == 0) {
    int h = lane & 7, g = lane >> 3;
    float s = bf2f(attb_s[h * 40 + g * 4 + 0]) + bf2f(attb_s[h * 40 + g * 4 + 1])
            + bf2f(attb_s[h * 40 + g * 4 + 2]) + bf2f(attb_s[h * 40 + g * 4 + 3]);
    s += __shfl_xor(s, 8, 64);
    s += __shfl_xor(s, 16, 64);
    s += __shfl_xor(s, 32, 64);
    if (lane < 8) is_s[h] = 1.f / s;
  }
  __syncthreads();

  // ---- Phase G: PV via MFMA. Wave w covers cols [64w, 64w+64).
  {
    bf16x8 af = *(const bf16x8*)&attb_s[fr * 40 + fg * 8];
#pragma unroll
    for (int nt = 0; nt < 4; nt++) {
      int colb = w * 64 + nt * 16;
      const u16* vbase = &kv_s[(fg * 8) * 260 + colb + fr];
      u16 b0 = vbase[0],        b1 = vbase[260],      b2 = vbase[2 * 260],
          b3 = vbase[3 * 260],  b4 = vbase[4 * 260],  b5 = vbase[5 * 260],
          b6 = vbase[6 * 260],  b7 = vbase[7 * 260];
      union { u32 u[4]; bf16x8 v; } bb;
      bb.u[0] = (u32)b0 | ((u32)b1 << 16);
      bb.u[1] = (u32)b2 | ((u32)b3 << 16);
      bb.u[2] = (u32)b4 | ((u32)b5 << 16);
      bb.u[3] = (u32)b6 | ((u32)b7 << 16);
      f32x4 acc = {0.f, 0.f, 0.f, 0.f};
      acc = __builtin_amdgcn_mfma_f32_16x16x32_bf16(af, bb.v, acc, 0, 0, 0);
      int h = 2 * w + (nt >> 1);
      if (fg == (w >> 1)) {
        float o = (w & 1) ? acc[2 + (nt >> 1)] : acc[0 + (nt >> 1)];
        out[(size_t)p * 256 + colb + fr] = o * is_s[h];
      }
    }
  }
}

// ---------------------------------------------------------------------------
extern "C" void kernel_launch(void* const* d_in, const int* in_sizes, int n_in,
                              void* d_out, int out_size, void* d_ws, size_t ws_size,
                              hipStream_t stream) {
  const float* query = (const float*)d_in[0];
  const float* key_x = (const float*)d_in[1];
  const float* value = (const float*)d_in[2];
  const int*   index_pair = (const int*)d_in[3];
  const float* raw  = (const float*)d_in[4];
  const float* rpe  = (const float*)d_in[5];
  const float* Wq = (const float*)d_in[6];
  const float* bq = (const float*)d_in[7];
  const float* Wk = (const float*)d_in[8];
  const float* bk = (const float*)d_in[9];
  const float* Wv = (const float*)d_in[10];
  const float* bv = (const float*)d_in[11];
  const float* Wg1 = (const float*)d_in[12];
  const float* bg1 = (const float*)d_in[13];
  const float* Wg2 = (const float*)d_in[14];
  const float* bg2 = (const float*)d_in[15];
  float* out = (float*)d_out;

  char* ws = (char*)d_ws;
  u16*   qbuf  = (u16*)(ws);                           // 4MB  [8192][256] bf16
  u16*   kbuf  = (u16*)(ws + (4u << 20));              // 4MB
  u16*   vbuf  = (u16*)(ws + (8u << 20));              // 4MB
  float* qadj  = (float*)(ws + (12u << 20));           // 1MB  [8192][32] f32
  float* kg1   = (float*)(ws + (13u << 20));           // 1MB
  u16*   WTq   = (u16*)(ws + (14u << 20));             // 128KB each
  u16*   WTk   = WTq + 65536;
  u16*   WTv   = WTk + 65536;
  u16*   CT    = WTv + 65536;                          // 2 x [32][256] bf16 (32KB)
  float* bcomb = (float*)(CT + 16384);                 // 48 f32
  u16*   wg2bf = (u16*)(bcomb + 64);                   // [32][40] bf16 (2560B)

  prep_transpose<<<dim3(8, 8, 3), dim3(32, 8, 1), 0, stream>>>(
      Wq, Wk, Wv, WTq, WTk, WTv);
  prep_wg2<<<1, 256, 0, stream>>>(Wg2, wg2bf);
  prep_comb<<<dim3(24, 2), 256, 0, stream>>>(
      WTq, WTk, Wg1, bg1, bq, bk, CT, bcomb);
  gemm_qkv<<<dim3(3, 64, 3), 256, 0, stream>>>(
      query, key_x, value, WTq, WTk, WTv, bq, bk, bv, CT, bcomb,
      qbuf, kbuf, vbuf, qadj, kg1);
  edge_attn<<<8192, 256, 0, stream>>>(
      qbuf, kbuf, vbuf, kg1, qadj, index_pair, raw, rpe, wg2bf, bg2, out);
}

// Round 6
// 80.955 us; speedup vs baseline: 1.1517x; 1.1517x over previous
//
#include <hip/hip_runtime.h>
#include <stdint.h>

typedef uint32_t u32;
typedef unsigned short u16;

#define LDT 40  // GEMM LDS row stride (elements)

typedef __bf16 bf16x8 __attribute__((ext_vector_type(8)));
typedef float  f32x4  __attribute__((ext_vector_type(4)));
typedef _Float16 h16x2 __attribute__((ext_vector_type(2)));

__device__ __forceinline__ float bf2f(u16 x) {
  union { float f; u32 u; } c; c.u = ((u32)x) << 16; return c.f;
}
__device__ __forceinline__ u16 f2bf(float f) {
  union { float f; u32 u; } c; c.f = f;
  u32 b = c.u;
  return (u16)((b + 0x7FFFu + ((b >> 16) & 1u)) >> 16);
}
__device__ __forceinline__ u32 pk2(float lo, float hi) {
  return (u32)f2bf(lo) | ((u32)f2bf(hi) << 16);
}
__device__ __forceinline__ u16 f2h(float f) {
  union { _Float16 h; u16 u; } c; c.h = (_Float16)f; return c.u;
}
__device__ __forceinline__ float h2f(u16 x) {
  union { _Float16 h; u16 u; } c; c.u = x; return (float)c.h;
}
__device__ __forceinline__ float fdot2u(u32 a, u32 b, float c) {
  union { u32 u; h16x2 h; } ua, ub; ua.u = a; ub.u = b;
#if __has_builtin(__builtin_amdgcn_fdot2)
  return __builtin_amdgcn_fdot2(ua.h, ub.h, c, false);
#else
  return c + (float)ua.h.x * (float)ub.h.x + (float)ua.h.y * (float)ub.h.y;
#endif
}

// ---------------------------------------------------------------------------
// Kernel 0: z<3: transpose+cast Wq/Wk/Wv (f32 [256][256] -> bf16 WT [n][k]).
//           z==3 (block 0,0 only): Wg2^T bf16 padded [32 j][40 i].
// ---------------------------------------------------------------------------
__global__ __launch_bounds__(256) void prep_transpose(
    const float* __restrict__ Wq, const float* __restrict__ Wk, const float* __restrict__ Wv,
    const float* __restrict__ Wg2,
    u16* __restrict__ WTq, u16* __restrict__ WTk, u16* __restrict__ WTv,
    u16* __restrict__ wg2bf)
{
  int z = blockIdx.z, bx = blockIdx.x, by = blockIdx.y;
  int x = threadIdx.x, y = threadIdx.y;  // 32 x 8
  if (z == 3) {
    if (bx || by) return;
    int t = y * 32 + x;
    for (int i = t; i < 1280; i += 256) {
      int j = i / 40, k = i % 40;
      float v = (j < 24 && k < 24) ? Wg2[(size_t)k * 24 + j] : 0.f;
      wg2bf[i] = f2bf(v);
    }
    return;
  }
  __shared__ u16 tile[32][33];
  const float* W  = (z == 0) ? Wq : (z == 1) ? Wk : Wv;
  u16*         WT = (z == 0) ? WTq : (z == 1) ? WTk : WTv;
  for (int yy = y; yy < 32; yy += 8)
    tile[yy][x] = f2bf(W[(size_t)(by * 32 + yy) * 256 + bx * 32 + x]);
  __syncthreads();
  for (int yy = y; yy < 32; yy += 8)
    WT[(size_t)(bx * 32 + yy) * 256 + by * 32 + x] = tile[x][yy];
}

// ---------------------------------------------------------------------------
// Kernel 0b: combined weights CT[z][c][k] = (W{q,k} @ Wg1)^T  (bf16, c<24),
//            bcomb[z][c] = b{q,k}@Wg1 (+ -bg1 for z=0)
// ---------------------------------------------------------------------------
__global__ __launch_bounds__(256) void prep_comb(
    const u16* __restrict__ WTq, const u16* __restrict__ WTk,
    const float* __restrict__ Wg1, const float* __restrict__ bg1,
    const float* __restrict__ bq, const float* __restrict__ bk,
    u16* __restrict__ CT, float* __restrict__ bcomb)
{
  int c = blockIdx.x, z = blockIdx.y;
  int t = threadIdx.x;
  const u16*   WT = (z == 0) ? WTq : WTk;
  const float* b  = (z == 0) ? bq : bk;

  float acc = 0.f;
#pragma unroll 8
  for (int e = 0; e < 256; e++)
    acc += bf2f(WT[(size_t)e * 256 + t]) * Wg1[(size_t)e * 24 + c];
  CT[(size_t)z * 8192 + (size_t)c * 256 + t] = f2bf(acc);

  __shared__ float red[256];
  red[t] = b[t] * Wg1[(size_t)t * 24 + c];
  __syncthreads();
  for (int s = 128; s > 0; s >>= 1) {
    if (t < s) red[t] += red[t + s];
    __syncthreads();
  }
  if (t == 0)
    bcomb[z * 24 + c] = red[0] - ((z == 0) ? bg1[c] : 0.f);
}

// ---------------------------------------------------------------------------
// Kernel 1: projections. blockIdx.x<2: Y[8192,256]=X@W+b (f16 out).
// blockIdx.x==2: extra 24 cols via combined weights -> qadj/kg1 (f32, stride 32).
// ---------------------------------------------------------------------------
__global__ __launch_bounds__(256) void gemm_qkv(
    const float* __restrict__ Xq, const float* __restrict__ Xk, const float* __restrict__ Xv,
    const u16* __restrict__ WTq, const u16* __restrict__ WTk, const u16* __restrict__ WTv,
    const float* __restrict__ bq, const float* __restrict__ bk, const float* __restrict__ bv,
    const u16* __restrict__ CT, const float* __restrict__ bcomb,
    u16* __restrict__ Oq, u16* __restrict__ Ok, u16* __restrict__ Ov,
    float* __restrict__ qadj, float* __restrict__ kg1)
{
  int z = blockIdx.z;
  int nblk = blockIdx.x;
  if (nblk == 2 && z == 2) return;

  const float* X = (z == 0) ? Xq : (z == 1) ? Xk : Xv;
  int m0 = blockIdx.y * 128;
  int t = threadIdx.x;
  int lane = t & 63, wid = t >> 6;
  int fr = lane & 15, fg = lane >> 4;
  int sr = t >> 1;
  int sc = (t & 1) * 16;

  __shared__ __align__(16) u16 la[128 * LDT];
  __shared__ __align__(16) u16 lb[128 * LDT];

  if (nblk < 2) {
    const u16*   WT   = (z == 0) ? WTq : (z == 1) ? WTk : WTv;
    const float* bias = (z == 0) ? bq : (z == 1) ? bk : bv;
    u16*         O    = (z == 0) ? Oq : (z == 1) ? Ok : Ov;
    int n0 = nblk * 128;
    int wr = wid >> 1, wc = wid & 1;

    f32x4 acc[4][4];
#pragma unroll
    for (int i = 0; i < 4; i++)
#pragma unroll
      for (int j = 0; j < 4; j++) acc[i][j] = (f32x4){0.f, 0.f, 0.f, 0.f};

    for (int kt = 0; kt < 256; kt += 32) {
      const float4* ga = (const float4*)(X + (size_t)(m0 + sr) * 256 + kt + sc);
      float4 a0 = ga[0], a1 = ga[1], a2 = ga[2], a3 = ga[3];
      const uint4* gb = (const uint4*)(WT + (size_t)(n0 + sr) * 256 + kt + sc);
      uint4 b0 = gb[0], b1 = gb[1];

      uint4 wa0, wa1;
      wa0.x = pk2(a0.x, a0.y); wa0.y = pk2(a0.z, a0.w);
      wa0.z = pk2(a1.x, a1.y); wa0.w = pk2(a1.z, a1.w);
      wa1.x = pk2(a2.x, a2.y); wa1.y = pk2(a2.z, a2.w);
      wa1.z = pk2(a3.x, a3.y); wa1.w = pk2(a3.z, a3.w);

      __syncthreads();
      *(uint4*)&la[sr * LDT + sc]     = wa0;
      *(uint4*)&la[sr * LDT + sc + 8] = wa1;
      *(uint4*)&lb[sr * LDT + sc]     = b0;
      *(uint4*)&lb[sr * LDT + sc + 8] = b1;
      __syncthreads();

      bf16x8 af[4], bfr[4];
#pragma unroll
      for (int s = 0; s < 4; s++)
        af[s] = *(const bf16x8*)&la[(wr * 64 + s * 16 + fr) * LDT + fg * 8];
#pragma unroll
      for (int s = 0; s < 4; s++)
        bfr[s] = *(const bf16x8*)&lb[(wc * 64 + s * 16 + fr) * LDT + fg * 8];
#pragma unroll
      for (int i = 0; i < 4; i++)
#pragma unroll
        for (int j = 0; j < 4; j++)
          acc[i][j] = __builtin_amdgcn_mfma_f32_16x16x32_bf16(af[i], bfr[j], acc[i][j], 0, 0, 0);
    }

#pragma unroll
    for (int i = 0; i < 4; i++) {
      int rowb = m0 + wr * 64 + i * 16 + fg * 4;
#pragma unroll
      for (int j = 0; j < 4; j++) {
        int col = n0 + wc * 64 + j * 16 + fr;
        float bb = bias[col];
#pragma unroll
        for (int r = 0; r < 4; r++)
          O[(size_t)(rowb + r) * 256 + col] = f2h(acc[i][j][r] + bb);
      }
    }
  } else {
    const u16*   BT = CT + (size_t)z * 8192;
    const float* bc = bcomb + z * 24;
    float*       O  = (z == 0) ? qadj : kg1;

    f32x4 acc[2][2];
#pragma unroll
    for (int i = 0; i < 2; i++)
#pragma unroll
      for (int j = 0; j < 2; j++) acc[i][j] = (f32x4){0.f, 0.f, 0.f, 0.f};

    for (int kt = 0; kt < 256; kt += 32) {
      const float4* ga = (const float4*)(X + (size_t)(m0 + sr) * 256 + kt + sc);
      float4 a0 = ga[0], a1 = ga[1], a2 = ga[2], a3 = ga[3];
      uint4 b0, b1;
      if (t < 64) {
        const uint4* gb = (const uint4*)(BT + (size_t)sr * 256 + kt + sc);
        b0 = gb[0]; b1 = gb[1];
      }
      uint4 wa0, wa1;
      wa0.x = pk2(a0.x, a0.y); wa0.y = pk2(a0.z, a0.w);
      wa0.z = pk2(a1.x, a1.y); wa0.w = pk2(a1.z, a1.w);
      wa1.x = pk2(a2.x, a2.y); wa1.y = pk2(a2.z, a2.w);
      wa1.z = pk2(a3.x, a3.y); wa1.w = pk2(a3.z, a3.w);

      __syncthreads();
      *(uint4*)&la[sr * LDT + sc]     = wa0;
      *(uint4*)&la[sr * LDT + sc + 8] = wa1;
      if (t < 64) {
        *(uint4*)&lb[sr * LDT + sc]     = b0;
        *(uint4*)&lb[sr * LDT + sc + 8] = b1;
      }
      __syncthreads();

      bf16x8 af[2], bfr[2];
#pragma unroll
      for (int s = 0; s < 2; s++)
        af[s] = *(const bf16x8*)&la[(wid * 32 + s * 16 + fr) * LDT + fg * 8];
#pragma unroll
      for (int s = 0; s < 2; s++)
        bfr[s] = *(const bf16x8*)&lb[(s * 16 + fr) * LDT + fg * 8];
#pragma unroll
      for (int i = 0; i < 2; i++)
#pragma unroll
        for (int j = 0; j < 2; j++)
          acc[i][j] = __builtin_amdgcn_mfma_f32_16x16x32_bf16(af[i], bfr[j], acc[i][j], 0, 0, 0);
    }

#pragma unroll
    for (int i = 0; i < 2; i++) {
      int rowb = m0 + wid * 32 + i * 16 + fg * 4;
#pragma unroll
      for (int j = 0; j < 2; j++) {
        int col = j * 16 + fr;
        if (col < 24) {
#pragma unroll
          for (int r = 0; r < 4; r++)
            O[(size_t)(rowb + r) * 32 + col] = acc[i][j][r] + bc[col];
        }
      }
    }
  }
}

// ---------------------------------------------------------------------------
// Kernel 2: fused edge/attention. 256 threads / point. Flat phases, MFMA only
// for the 24x24 MLP. q/k read from global (f16, fdot2); V staged in LDS.
// ---------------------------------------------------------------------------
__global__ __launch_bounds__(256) void edge_attn(
    const u16* __restrict__ qb, const u16* __restrict__ kb, const u16* __restrict__ vb,
    const float* __restrict__ kg1g, const float* __restrict__ qadjg,
    const int* __restrict__ ip, const float* __restrict__ raw,
    const float* __restrict__ rpe, const u16* __restrict__ wg2bf,
    const float* __restrict__ bg2g, float* __restrict__ out)
{
  int p = blockIdx.x, t = threadIdx.x;
  int lane = t & 63, w = t >> 6;
  int fr = lane & 15, fg = lane >> 4;
  int n = t >> 3, h = t & 7;

  __shared__ __align__(16) u16   v_s[32 * 264];    // f16 gathered V rows
  __shared__ __align__(16) u16   wg2_s[32 * 40];   // bf16 Wg2^T padded
  __shared__ __align__(16) float kg1_s[32 * 36];
  __shared__              float qadj_s[24];
  __shared__              float bg2_s[24];
  __shared__              float sh_s[32 * 3];
  __shared__              float g_s[32 * 33];
  __shared__              float att_s[32 * 8];     // e-values, then normalized
  __shared__              float is_s[8];

  int myidx = ip[(size_t)p * 32 + n];   // same n for v-gather, kg1-gather, dot

  // ---- Phase A: staging
  {
    int c0 = (t & 7) * 32;  // f16 elems
    const uint4* vp = (const uint4*)(vb + (size_t)myidx * 256 + c0);
    uint4 a = vp[0], b = vp[1], c = vp[2], d = vp[3];
    u16* dst = &v_s[n * 264 + c0];
    ((uint4*)dst)[0] = a; ((uint4*)dst)[1] = b;
    ((uint4*)dst)[2] = c; ((uint4*)dst)[3] = d;
  }
  if ((t & 7) < 6)
    *(float4*)&kg1_s[n * 36 + (t & 7) * 4] =
        *(const float4*)(kg1g + (size_t)myidx * 32 + (t & 7) * 4);
  if (t < 160) *(uint4*)&wg2_s[t * 8] = ((const uint4*)wg2bf)[t];
  else if (t < 192) {
    int nn = t - 160;
    float x  = rpe[(size_t)p * 96 + nn * 3 + 0];
    float y  = rpe[(size_t)p * 96 + nn * 3 + 1];
    float z  = rpe[(size_t)p * 96 + nn * 3 + 2];
    float rl = sqrtf(x * x + y * y + z * z);
    float inv = 1.f / fmaxf(rl, 1e-12f);
    float tt2 = fminf(fmaxf((rl - 0.001f) * 250.f, 0.f), 1.f);
    float cut = 0.5f * (1.f - cosf(tt2 * 3.14159265358979f));
    float s3c = 1.7320508075688772f * inv * cut;
    sh_s[nn * 3 + 0] = x * s3c; sh_s[nn * 3 + 1] = y * s3c; sh_s[nn * 3 + 2] = z * s3c;
  }
  else if (t >= 192 && t < 216) qadj_s[t - 192] = qadjg[(size_t)p * 32 + (t - 192)];
  else if (t >= 224 && t < 248) bg2_s[t - 224] = bg2g[t - 224];
  __syncthreads();

  // ---- Phase B: MLP g = relu(kg1_g - qadj) @ Wg2 + bg2 (1 MFMA per wave)
  {
    int mt = w & 1, jt = w >> 1;
    union { u32 u[4]; bf16x8 v; } a;
    if (fg < 3) {
      const float* kr = &kg1_s[(mt * 16 + fr) * 36 + fg * 8];
      const float* qr = &qadj_s[fg * 8];
      float x0 = fmaxf(kr[0] - qr[0], 0.f), x1 = fmaxf(kr[1] - qr[1], 0.f);
      float x2 = fmaxf(kr[2] - qr[2], 0.f), x3 = fmaxf(kr[3] - qr[3], 0.f);
      float x4 = fmaxf(kr[4] - qr[4], 0.f), x5 = fmaxf(kr[5] - qr[5], 0.f);
      float x6 = fmaxf(kr[6] - qr[6], 0.f), x7 = fmaxf(kr[7] - qr[7], 0.f);
      a.u[0] = pk2(x0, x1); a.u[1] = pk2(x2, x3);
      a.u[2] = pk2(x4, x5); a.u[3] = pk2(x6, x7);
    } else {
      a.u[0] = a.u[1] = a.u[2] = a.u[3] = 0;
    }
    bf16x8 b = *(const bf16x8*)&wg2_s[(jt * 16 + fr) * 40 + fg * 8];
    f32x4 g = (f32x4){0.f, 0.f, 0.f, 0.f};
    g = __builtin_amdgcn_mfma_f32_16x16x32_bf16(a.v, b, g, 0, 0, 0);
    int j = jt * 16 + fr;
    float bb = (j < 24) ? bg2_s[j] : 0.f;
    int e0 = mt * 16 + fg * 4;
#pragma unroll
    for (int r = 0; r < 4; r++)
      g_s[(e0 + r) * 33 + j] = g[r] + bb;
  }
  __syncthreads();

  // ---- Phase C: logits + exp (max-free, f32-safe) -> att_s e-values
  float ev;
  {
    const uint4* kr = (const uint4*)(kb + (size_t)myidx * 256 + h * 32);
    const uint4* qr = (const uint4*)(qb + (size_t)p * 256 + h * 32);
    float dot = 0.f;
#pragma unroll
    for (int c = 0; c < 4; c++) {
      uint4 kw = kr[c], qw = qr[c];
      dot = fdot2u(kw.x, qw.x, dot);
      dot = fdot2u(kw.y, qw.y, dot);
      dot = fdot2u(kw.z, qw.z, dot);
      dot = fdot2u(kw.w, qw.w, dot);
    }
    float pos = g_s[n * 33 + h * 3 + 0] * sh_s[n * 3 + 0]
              + g_s[n * 33 + h * 3 + 1] * sh_s[n * 3 + 1]
              + g_s[n * 33 + h * 3 + 2] * sh_s[n * 3 + 2];
    float rw = raw[(size_t)p * 256 + t];
    ev = __expf((dot + pos + rw) * 0.17677669529663687f);
    att_s[t] = ev;
  }
  __syncthreads();

  // ---- Phase D: softmax denominators (wave 0)
  if (w == 0) {
    int hh = lane & 7, g4 = lane >> 3;
    float s = att_s[(g4 * 4 + 0) * 8 + hh] + att_s[(g4 * 4 + 1) * 8 + hh]
            + att_s[(g4 * 4 + 2) * 8 + hh] + att_s[(g4 * 4 + 3) * 8 + hh];
    s += __shfl_xor(s, 8, 64);
    s += __shfl_xor(s, 16, 64);
    s += __shfl_xor(s, 32, 64);
    if (lane < 8) is_s[hh] = 1.f / s;
  }
  __syncthreads();

  // ---- Phase E: normalize (e-value still in register)
  att_s[t] = ev * is_s[h];
  __syncthreads();

  // ---- Phase F: PV from LDS. thread = output col t.
  {
    int ch = t >> 5;
    const u16* vcol = &v_s[t];
    const float* acol = &att_s[ch];
    float acc = 0.f;
#pragma unroll
    for (int nn = 0; nn < 32; nn++)
      acc += acol[nn * 8] * h2f(vcol[nn * 264]);
    out[(size_t)p * 256 + t] = acc;
  }
}

// ---------------------------------------------------------------------------
extern "C" void kernel_launch(void* const* d_in, const int* in_sizes, int n_in,
                              void* d_out, int out_size, void* d_ws, size_t ws_size,
                              hipStream_t stream) {
  const float* query = (const float*)d_in[0];
  const float* key_x = (const float*)d_in[1];
  const float* value = (const float*)d_in[2];
  const int*   index_pair = (const int*)d_in[3];
  const float* raw  = (const float*)d_in[4];
  const float* rpe  = (const float*)d_in[5];
  const float* Wq = (const float*)d_in[6];
  const float* bq = (const float*)d_in[7];
  const float* Wk = (const float*)d_in[8];
  const float* bk = (const float*)d_in[9];
  const float* Wv = (const float*)d_in[10];
  const float* bv = (const float*)d_in[11];
  const float* Wg1 = (const float*)d_in[12];
  const float* bg1 = (const float*)d_in[13];
  const float* Wg2 = (const float*)d_in[14];
  const float* bg2 = (const float*)d_in[15];
  float* out = (float*)d_out;

  char* ws = (char*)d_ws;
  u16*   qbuf  = (u16*)(ws);                           // 4MB  [8192][256] f16
  u16*   kbuf  = (u16*)(ws + (4u << 20));              // 4MB
  u16*   vbuf  = (u16*)(ws + (8u << 20));              // 4MB
  float* qadj  = (float*)(ws + (12u << 20));           // 1MB  [8192][32] f32
  float* kg1   = (float*)(ws + (13u << 20));           // 1MB
  u16*   WTq   = (u16*)(ws + (14u << 20));             // 128KB each
  u16*   WTk   = WTq + 65536;
  u16*   WTv   = WTk + 65536;
  u16*   CT    = WTv + 65536;                          // 2 x [32][256] bf16 (32KB)
  float* bcomb = (float*)(CT + 16384);                 // 48 f32
  u16*   wg2bf = (u16*)(bcomb + 64);                   // [32][40] bf16 (2560B)

  prep_transpose<<<dim3(8, 8, 4), dim3(32, 8, 1), 0, stream>>>(
      Wq, Wk, Wv, Wg2, WTq, WTk, WTv, wg2bf);
  prep_comb<<<dim3(24, 2), 256, 0, stream>>>(
      WTq, WTk, Wg1, bg1, bq, bk, CT, bcomb);
  gemm_qkv<<<dim3(3, 64, 3), 256, 0, stream>>>(
      query, key_x, value, WTq, WTk, WTv, bq, bk, bv, CT, bcomb,
      qbuf, kbuf, vbuf, qadj, kg1);
  edge_attn<<<8192, 256, 0, stream>>>(
      qbuf, kbuf, vbuf, kg1, qadj, index_pair, raw, rpe, wg2bf, bg2, out);
}

// Round 7
// 77.025 us; speedup vs baseline: 1.2104x; 1.0510x over previous
//
#include <hip/hip_runtime.h>
#include <stdint.h>

typedef uint32_t u32;
typedef unsigned short u16;

#define LDT 40  // GEMM LDS row stride (elements)

typedef __bf16 bf16x8 __attribute__((ext_vector_type(8)));
typedef float  f32x4  __attribute__((ext_vector_type(4)));
typedef _Float16 h16x2 __attribute__((ext_vector_type(2)));

__device__ __forceinline__ float bf2f(u16 x) {
  union { float f; u32 u; } c; c.u = ((u32)x) << 16; return c.f;
}
__device__ __forceinline__ u16 f2bf(float f) {
  union { float f; u32 u; } c; c.f = f;
  u32 b = c.u;
  return (u16)((b + 0x7FFFu + ((b >> 16) & 1u)) >> 16);
}
__device__ __forceinline__ u32 pk2(float lo, float hi) {
  return (u32)f2bf(lo) | ((u32)f2bf(hi) << 16);
}
__device__ __forceinline__ u16 f2h(float f) {
  union { _Float16 h; u16 u; } c; c.h = (_Float16)f; return c.u;
}
__device__ __forceinline__ float h2f(u16 x) {
  union { _Float16 h; u16 u; } c; c.u = x; return (float)c.h;
}
__device__ __forceinline__ float fdot2u(u32 a, u32 b, float c) {
  union { u32 u; h16x2 h; } ua, ub; ua.u = a; ub.u = b;
#if __has_builtin(__builtin_amdgcn_fdot2)
  return __builtin_amdgcn_fdot2(ua.h, ub.h, c, false);
#else
  return c + (float)ua.h.x * (float)ub.h.x + (float)ua.h.y * (float)ub.h.y;
#endif
}

// ---------------------------------------------------------------------------
// Kernel 0: z<3: transpose+cast Wq/Wk/Wv (f32 [256][256] -> bf16 WT [n][k]).
//           z==3 (block 0,0 only): Wg2^T bf16 padded [32 j][40 i].
// ---------------------------------------------------------------------------
__global__ __launch_bounds__(256) void prep_transpose(
    const float* __restrict__ Wq, const float* __restrict__ Wk, const float* __restrict__ Wv,
    const float* __restrict__ Wg2,
    u16* __restrict__ WTq, u16* __restrict__ WTk, u16* __restrict__ WTv,
    u16* __restrict__ wg2bf)
{
  int z = blockIdx.z, bx = blockIdx.x, by = blockIdx.y;
  int x = threadIdx.x, y = threadIdx.y;  // 32 x 8
  if (z == 3) {
    if (bx || by) return;
    int t = y * 32 + x;
    for (int i = t; i < 1280; i += 256) {
      int j = i / 40, k = i % 40;
      float v = (j < 24 && k < 24) ? Wg2[(size_t)k * 24 + j] : 0.f;
      wg2bf[i] = f2bf(v);
    }
    return;
  }
  __shared__ u16 tile[32][33];
  const float* W  = (z == 0) ? Wq : (z == 1) ? Wk : Wv;
  u16*         WT = (z == 0) ? WTq : (z == 1) ? WTk : WTv;
  for (int yy = y; yy < 32; yy += 8)
    tile[yy][x] = f2bf(W[(size_t)(by * 32 + yy) * 256 + bx * 32 + x]);
  __syncthreads();
  for (int yy = y; yy < 32; yy += 8)
    WT[(size_t)(bx * 32 + yy) * 256 + by * 32 + x] = tile[x][yy];
}

// ---------------------------------------------------------------------------
// Kernel 0b: combined weights CT[z][c][k] = (W{q,k} @ Wg1)^T  (bf16, c<24),
//            bcomb[z][c] = b{q,k}@Wg1 (+ -bg1 for z=0)
// ---------------------------------------------------------------------------
__global__ __launch_bounds__(256) void prep_comb(
    const u16* __restrict__ WTq, const u16* __restrict__ WTk,
    const float* __restrict__ Wg1, const float* __restrict__ bg1,
    const float* __restrict__ bq, const float* __restrict__ bk,
    u16* __restrict__ CT, float* __restrict__ bcomb)
{
  int c = blockIdx.x, z = blockIdx.y;
  int t = threadIdx.x;
  const u16*   WT = (z == 0) ? WTq : WTk;
  const float* b  = (z == 0) ? bq : bk;

  float acc = 0.f;
#pragma unroll 8
  for (int e = 0; e < 256; e++)
    acc += bf2f(WT[(size_t)e * 256 + t]) * Wg1[(size_t)e * 24 + c];
  CT[(size_t)z * 8192 + (size_t)c * 256 + t] = f2bf(acc);

  __shared__ float red[256];
  red[t] = b[t] * Wg1[(size_t)t * 24 + c];
  __syncthreads();
  for (int s = 128; s > 0; s >>= 1) {
    if (t < s) red[t] += red[t + s];
    __syncthreads();
  }
  if (t == 0)
    bcomb[z * 24 + c] = red[0] - ((z == 0) ? bg1[c] : 0.f);
}

// ---------------------------------------------------------------------------
// Kernel 1: projections. grid (64 m-tiles, 3 n-blks, 3 matrices).
// nblk<2: Y[8192,256]=X@W+b (f16 out). nblk==2: 24 extra cols via combined
// weights -> qadj/kg1 (f16, stride 32). Same-m blocks are blockIdx stride 64
// apart -> same XCD -> X tile fetched once.
// ---------------------------------------------------------------------------
__global__ __launch_bounds__(256) void gemm_qkv(
    const float* __restrict__ Xq, const float* __restrict__ Xk, const float* __restrict__ Xv,
    const u16* __restrict__ WTq, const u16* __restrict__ WTk, const u16* __restrict__ WTv,
    const float* __restrict__ bq, const float* __restrict__ bk, const float* __restrict__ bv,
    const u16* __restrict__ CT, const float* __restrict__ bcomb,
    u16* __restrict__ Oq, u16* __restrict__ Ok, u16* __restrict__ Ov,
    u16* __restrict__ qadj, u16* __restrict__ kg1)
{
  int z = blockIdx.z;
  int nblk = blockIdx.y;
  if (nblk == 2 && z == 2) return;

  const float* X = (z == 0) ? Xq : (z == 1) ? Xk : Xv;
  int m0 = blockIdx.x * 128;
  int t = threadIdx.x;
  int lane = t & 63, wid = t >> 6;
  int fr = lane & 15, fg = lane >> 4;
  int sr = t >> 1;
  int sc = (t & 1) * 16;

  __shared__ __align__(16) u16 la[128 * LDT];
  __shared__ __align__(16) u16 lb[128 * LDT];

  if (nblk < 2) {
    const u16*   WT   = (z == 0) ? WTq : (z == 1) ? WTk : WTv;
    const float* bias = (z == 0) ? bq : (z == 1) ? bk : bv;
    u16*         O    = (z == 0) ? Oq : (z == 1) ? Ok : Ov;
    int n0 = nblk * 128;
    int wr = wid >> 1, wc = wid & 1;

    f32x4 acc[4][4];
#pragma unroll
    for (int i = 0; i < 4; i++)
#pragma unroll
      for (int j = 0; j < 4; j++) acc[i][j] = (f32x4){0.f, 0.f, 0.f, 0.f};

    for (int kt = 0; kt < 256; kt += 32) {
      const float4* ga = (const float4*)(X + (size_t)(m0 + sr) * 256 + kt + sc);
      float4 a0 = ga[0], a1 = ga[1], a2 = ga[2], a3 = ga[3];
      const uint4* gb = (const uint4*)(WT + (size_t)(n0 + sr) * 256 + kt + sc);
      uint4 b0 = gb[0], b1 = gb[1];

      uint4 wa0, wa1;
      wa0.x = pk2(a0.x, a0.y); wa0.y = pk2(a0.z, a0.w);
      wa0.z = pk2(a1.x, a1.y); wa0.w = pk2(a1.z, a1.w);
      wa1.x = pk2(a2.x, a2.y); wa1.y = pk2(a2.z, a2.w);
      wa1.z = pk2(a3.x, a3.y); wa1.w = pk2(a3.z, a3.w);

      __syncthreads();
      *(uint4*)&la[sr * LDT + sc]     = wa0;
      *(uint4*)&la[sr * LDT + sc + 8] = wa1;
      *(uint4*)&lb[sr * LDT + sc]     = b0;
      *(uint4*)&lb[sr * LDT + sc + 8] = b1;
      __syncthreads();

      bf16x8 af[4], bfr[4];
#pragma unroll
      for (int s = 0; s < 4; s++)
        af[s] = *(const bf16x8*)&la[(wr * 64 + s * 16 + fr) * LDT + fg * 8];
#pragma unroll
      for (int s = 0; s < 4; s++)
        bfr[s] = *(const bf16x8*)&lb[(wc * 64 + s * 16 + fr) * LDT + fg * 8];
#pragma unroll
      for (int i = 0; i < 4; i++)
#pragma unroll
        for (int j = 0; j < 4; j++)
          acc[i][j] = __builtin_amdgcn_mfma_f32_16x16x32_bf16(af[i], bfr[j], acc[i][j], 0, 0, 0);
    }

#pragma unroll
    for (int i = 0; i < 4; i++) {
      int rowb = m0 + wr * 64 + i * 16 + fg * 4;
#pragma unroll
      for (int j = 0; j < 4; j++) {
        int col = n0 + wc * 64 + j * 16 + fr;
        float bb = bias[col];
#pragma unroll
        for (int r = 0; r < 4; r++)
          O[(size_t)(rowb + r) * 256 + col] = f2h(acc[i][j][r] + bb);
      }
    }
  } else {
    const u16*   BT = CT + (size_t)z * 8192;
    const float* bc = bcomb + z * 24;
    u16*         O  = (z == 0) ? qadj : kg1;

    f32x4 acc[2][2];
#pragma unroll
    for (int i = 0; i < 2; i++)
#pragma unroll
      for (int j = 0; j < 2; j++) acc[i][j] = (f32x4){0.f, 0.f, 0.f, 0.f};

    for (int kt = 0; kt < 256; kt += 32) {
      const float4* ga = (const float4*)(X + (size_t)(m0 + sr) * 256 + kt + sc);
      float4 a0 = ga[0], a1 = ga[1], a2 = ga[2], a3 = ga[3];
      uint4 b0, b1;
      if (t < 64) {
        const uint4* gb = (const uint4*)(BT + (size_t)sr * 256 + kt + sc);
        b0 = gb[0]; b1 = gb[1];
      }
      uint4 wa0, wa1;
      wa0.x = pk2(a0.x, a0.y); wa0.y = pk2(a0.z, a0.w);
      wa0.z = pk2(a1.x, a1.y); wa0.w = pk2(a1.z, a1.w);
      wa1.x = pk2(a2.x, a2.y); wa1.y = pk2(a2.z, a2.w);
      wa1.z = pk2(a3.x, a3.y); wa1.w = pk2(a3.z, a3.w);

      __syncthreads();
      *(uint4*)&la[sr * LDT + sc]     = wa0;
      *(uint4*)&la[sr * LDT + sc + 8] = wa1;
      if (t < 64) {
        *(uint4*)&lb[sr * LDT + sc]     = b0;
        *(uint4*)&lb[sr * LDT + sc + 8] = b1;
      }
      __syncthreads();

      bf16x8 af[2], bfr[2];
#pragma unroll
      for (int s = 0; s < 2; s++)
        af[s] = *(const bf16x8*)&la[(wid * 32 + s * 16 + fr) * LDT + fg * 8];
#pragma unroll
      for (int s = 0; s < 2; s++)
        bfr[s] = *(const bf16x8*)&lb[(s * 16 + fr) * LDT + fg * 8];
#pragma unroll
      for (int i = 0; i < 2; i++)
#pragma unroll
        for (int j = 0; j < 2; j++)
          acc[i][j] = __builtin_amdgcn_mfma_f32_16x16x32_bf16(af[i], bfr[j], acc[i][j], 0, 0, 0);
    }

#pragma unroll
    for (int i = 0; i < 2; i++) {
      int rowb = m0 + wid * 32 + i * 16 + fg * 4;
#pragma unroll
      for (int j = 0; j < 2; j++) {
        int col = j * 16 + fr;
        if (col < 24) {
#pragma unroll
          for (int r = 0; r < 4; r++)
            O[(size_t)(rowb + r) * 32 + col] = f2h(acc[i][j][r] + bc[col]);
        }
      }
    }
  }
}

// ---------------------------------------------------------------------------
// Kernel 2: logits + softmax -> att f16 [P][32 n][8 h], normalized.
// Gathers ONLY kbuf (4MB) + kg1 (0.5MB) -> fits per-XCD L2.
// ---------------------------------------------------------------------------
__global__ __launch_bounds__(256) void attn_logits(
    const u16* __restrict__ qb, const u16* __restrict__ kb,
    const u16* __restrict__ kg1g, const u16* __restrict__ qadjg,
    const int* __restrict__ ip, const float* __restrict__ raw,
    const float* __restrict__ rpe, const u16* __restrict__ wg2bf,
    const float* __restrict__ bg2g, u16* __restrict__ attg)
{
  int p = blockIdx.x, t = threadIdx.x;
  int lane = t & 63, w = t >> 6;
  int fr = lane & 15, fg = lane >> 4;
  int n = t >> 3, h = t & 7;

  __shared__ __align__(16) u16   wg2_s[32 * 40];   // bf16 Wg2^T padded
  __shared__ __align__(16) u16   kg1_s[32 * 40];   // f16 gathered kg1 rows
  __shared__              float qadj_s[24];
  __shared__              float bg2_s[24];
  __shared__              float sh_s[96];
  __shared__              float g_s[32 * 33];
  __shared__              float ev_s[256];
  __shared__              float is_s[8];

  int myidx = ip[(size_t)p * 32 + n];
  float rw = raw[(size_t)p * 256 + t];   // hoisted stream read

  // ---- Phase A: staging
  if ((t & 7) < 4)
    *(uint4*)&kg1_s[n * 40 + (t & 7) * 8] =
        *(const uint4*)(kg1g + (size_t)myidx * 32 + (t & 7) * 8);
  if (t < 160) *(uint4*)&wg2_s[t * 8] = ((const uint4*)wg2bf)[t];
  else if (t < 192) {
    int nn = t - 160;
    float x  = rpe[(size_t)p * 96 + nn * 3 + 0];
    float y  = rpe[(size_t)p * 96 + nn * 3 + 1];
    float z  = rpe[(size_t)p * 96 + nn * 3 + 2];
    float rl = sqrtf(x * x + y * y + z * z);
    float inv = 1.f / fmaxf(rl, 1e-12f);
    float tt2 = fminf(fmaxf((rl - 0.001f) * 250.f, 0.f), 1.f);
    float cut = 0.5f * (1.f - cosf(tt2 * 3.14159265358979f));
    float s3c = 1.7320508075688772f * inv * cut;
    sh_s[nn * 3 + 0] = x * s3c; sh_s[nn * 3 + 1] = y * s3c; sh_s[nn * 3 + 2] = z * s3c;
  }
  else if (t >= 192 && t < 216) qadj_s[t - 192] = h2f(qadjg[(size_t)p * 32 + (t - 192)]);
  else if (t >= 224 && t < 248) bg2_s[t - 224] = bg2g[t - 224];
  __syncthreads();

  // ---- Phase B: MLP g = relu(kg1_g - qadj) @ Wg2 + bg2 (1 MFMA per wave)
  {
    int mt = w & 1, jt = w >> 1;
    union { u32 u[4]; bf16x8 v; } a;
    if (fg < 3) {
      const u16*   kr = &kg1_s[(mt * 16 + fr) * 40 + fg * 8];
      const float* qr = &qadj_s[fg * 8];
      float x0 = fmaxf(h2f(kr[0]) - qr[0], 0.f), x1 = fmaxf(h2f(kr[1]) - qr[1], 0.f);
      float x2 = fmaxf(h2f(kr[2]) - qr[2], 0.f), x3 = fmaxf(h2f(kr[3]) - qr[3], 0.f);
      float x4 = fmaxf(h2f(kr[4]) - qr[4], 0.f), x5 = fmaxf(h2f(kr[5]) - qr[5], 0.f);
      float x6 = fmaxf(h2f(kr[6]) - qr[6], 0.f), x7 = fmaxf(h2f(kr[7]) - qr[7], 0.f);
      a.u[0] = pk2(x0, x1); a.u[1] = pk2(x2, x3);
      a.u[2] = pk2(x4, x5); a.u[3] = pk2(x6, x7);
    } else {
      a.u[0] = a.u[1] = a.u[2] = a.u[3] = 0;
    }
    bf16x8 b = *(const bf16x8*)&wg2_s[(jt * 16 + fr) * 40 + fg * 8];
    f32x4 g = (f32x4){0.f, 0.f, 0.f, 0.f};
    g = __builtin_amdgcn_mfma_f32_16x16x32_bf16(a.v, b, g, 0, 0, 0);
    int j = jt * 16 + fr;
    float bb = (j < 24) ? bg2_s[j] : 0.f;
    int e0 = mt * 16 + fg * 4;
#pragma unroll
    for (int r = 0; r < 4; r++)
      g_s[(e0 + r) * 33 + j] = g[r] + bb;
  }
  __syncthreads();

  // ---- Phase C: dot (k gather, fdot2) + pos + raw -> e-values
  float ev;
  {
    const uint4* kr = (const uint4*)(kb + (size_t)myidx * 256 + h * 32);
    const uint4* qr = (const uint4*)(qb + (size_t)p * 256 + h * 32);
    float dot = 0.f;
#pragma unroll
    for (int c = 0; c < 4; c++) {
      uint4 kw = kr[c], qw = qr[c];
      dot = fdot2u(kw.x, qw.x, dot);
      dot = fdot2u(kw.y, qw.y, dot);
      dot = fdot2u(kw.z, qw.z, dot);
      dot = fdot2u(kw.w, qw.w, dot);
    }
    float pos = g_s[n * 33 + h * 3 + 0] * sh_s[n * 3 + 0]
              + g_s[n * 33 + h * 3 + 1] * sh_s[n * 3 + 1]
              + g_s[n * 33 + h * 3 + 2] * sh_s[n * 3 + 2];
    ev = __expf((dot + pos + rw) * 0.17677669529663687f);
    ev_s[t] = ev;
  }
  __syncthreads();

  // ---- Phase D: denominators (wave 0)
  if (w == 0) {
    int hh = lane & 7, g4 = lane >> 3;
    float s = ev_s[(g4 * 4 + 0) * 8 + hh] + ev_s[(g4 * 4 + 1) * 8 + hh]
            + ev_s[(g4 * 4 + 2) * 8 + hh] + ev_s[(g4 * 4 + 3) * 8 + hh];
    s += __shfl_xor(s, 8, 64);
    s += __shfl_xor(s, 16, 64);
    s += __shfl_xor(s, 32, 64);
    if (lane < 8) is_s[hh] = 1.f / s;
  }
  __syncthreads();

  // ---- Phase E: normalized att f16 out
  attg[(size_t)p * 256 + t] = f2h(ev * is_s[h]);
}

// ---------------------------------------------------------------------------
// Kernel 3: PV. 4 points/block, 1 wave/point (wave-private, no barrier).
// Gathers ONLY vbuf (4MB) -> fits per-XCD L2.
// ---------------------------------------------------------------------------
__global__ __launch_bounds__(256) void attn_pv(
    const u16* __restrict__ vb, const u16* __restrict__ attg,
    const int* __restrict__ ip, float* __restrict__ out)
{
  int t = threadIdx.x, wid = t >> 6, l = t & 63;
  int p = blockIdx.x * 4 + wid;
  __shared__ __align__(8) u16 att_s[4][256];
  __shared__ int idx_s[4][32];

  *(uint2*)&att_s[wid][l * 4] = *(const uint2*)(attg + (size_t)p * 256 + l * 4);
  if (l < 32) idx_s[wid][l] = ip[(size_t)p * 32 + l];

  int hh = l >> 3;
  float a0 = 0.f, a1 = 0.f, a2 = 0.f, a3 = 0.f;
#pragma unroll
  for (int n = 0; n < 32; n++) {
    float wt = h2f(att_s[wid][n * 8 + hh]);
    uint2 vv = *(const uint2*)(vb + (size_t)idx_s[wid][n] * 256 + l * 4);
    a0 += wt * h2f((u16)(vv.x & 0xFFFF));
    a1 += wt * h2f((u16)(vv.x >> 16));
    a2 += wt * h2f((u16)(vv.y & 0xFFFF));
    a3 += wt * h2f((u16)(vv.y >> 16));
  }
  float4 r; r.x = a0; r.y = a1; r.z = a2; r.w = a3;
  *(float4*)(out + (size_t)p * 256 + l * 4) = r;
}

// ---------------------------------------------------------------------------
extern "C" void kernel_launch(void* const* d_in, const int* in_sizes, int n_in,
                              void* d_out, int out_size, void* d_ws, size_t ws_size,
                              hipStream_t stream) {
  const float* query = (const float*)d_in[0];
  const float* key_x = (const float*)d_in[1];
  const float* value = (const float*)d_in[2];
  const int*   index_pair = (const int*)d_in[3];
  const float* raw  = (const float*)d_in[4];
  const float* rpe  = (const float*)d_in[5];
  const float* Wq = (const float*)d_in[6];
  const float* bq = (const float*)d_in[7];
  const float* Wk = (const float*)d_in[8];
  const float* bk = (const float*)d_in[9];
  const float* Wv = (const float*)d_in[10];
  const float* bv = (const float*)d_in[11];
  const float* Wg1 = (const float*)d_in[12];
  const float* bg1 = (const float*)d_in[13];
  const float* Wg2 = (const float*)d_in[14];
  const float* bg2 = (const float*)d_in[15];
  float* out = (float*)d_out;

  char* ws = (char*)d_ws;
  u16*   qbuf  = (u16*)(ws);                           // 4MB  [8192][256] f16
  u16*   kbuf  = (u16*)(ws + (4u << 20));              // 4MB
  u16*   vbuf  = (u16*)(ws + (8u << 20));              // 4MB
  u16*   attb  = (u16*)(ws + (12u << 20));             // 4MB  [8192][32][8] f16
  u16*   qadj  = (u16*)(ws + (16u << 20));             // 512KB [8192][32] f16
  u16*   kg1   = (u16*)(ws + (16u << 20) + 524288);    // 512KB
  u16*   WTq   = (u16*)(ws + (17u << 20));             // 128KB each
  u16*   WTk   = WTq + 65536;
  u16*   WTv   = WTk + 65536;
  u16*   CT    = WTv + 65536;                          // 2 x [32][256] bf16 (32KB)
  float* bcomb = (float*)(CT + 16384);                 // 48 f32
  u16*   wg2bf = (u16*)(bcomb + 64);                   // [32][40] bf16 (2560B)

  prep_transpose<<<dim3(8, 8, 4), dim3(32, 8, 1), 0, stream>>>(
      Wq, Wk, Wv, Wg2, WTq, WTk, WTv, wg2bf);
  prep_comb<<<dim3(24, 2), 256, 0, stream>>>(
      WTq, WTk, Wg1, bg1, bq, bk, CT, bcomb);
  gemm_qkv<<<dim3(64, 3, 3), 256, 0, stream>>>(
      query, key_x, value, WTq, WTk, WTv, bq, bk, bv, CT, bcomb,
      qbuf, kbuf, vbuf, qadj, kg1);
  attn_logits<<<8192, 256, 0, stream>>>(
      qbuf, kbuf, kg1, qadj, index_pair, raw, rpe, wg2bf, bg2, attb);
  attn_pv<<<2048, 256, 0, stream>>>(
      vbuf, attb, index_pair, out);
}

// Round 8
// 72.690 us; speedup vs baseline: 1.2826x; 1.0596x over previous
//
#include <hip/hip_runtime.h>
#include <stdint.h>

typedef uint32_t u32;
typedef unsigned short u16;

#define LDT 40  // GEMM LDS row stride (elements)

typedef __bf16 bf16x8 __attribute__((ext_vector_type(8)));
typedef float  f32x4  __attribute__((ext_vector_type(4)));
typedef _Float16 h16x2 __attribute__((ext_vector_type(2)));
typedef u32    u32x4  __attribute__((ext_vector_type(4)));
typedef u32    u32x2  __attribute__((ext_vector_type(2)));
typedef float  f32x4v __attribute__((ext_vector_type(4)));

__device__ __forceinline__ float bf2f(u16 x) {
  union { float f; u32 u; } c; c.u = ((u32)x) << 16; return c.f;
}
__device__ __forceinline__ u16 f2bf(float f) {
  union { float f; u32 u; } c; c.f = f;
  u32 b = c.u;
  return (u16)((b + 0x7FFFu + ((b >> 16) & 1u)) >> 16);
}
__device__ __forceinline__ u32 pk2(float lo, float hi) {
  return (u32)f2bf(lo) | ((u32)f2bf(hi) << 16);
}
__device__ __forceinline__ u16 f2h(float f) {
  union { _Float16 h; u16 u; } c; c.h = (_Float16)f; return c.u;
}
__device__ __forceinline__ float h2f(u16 x) {
  union { _Float16 h; u16 u; } c; c.u = x; return (float)c.h;
}
__device__ __forceinline__ u32 h2bf2(u32 w) {  // 2 f16 -> 2 bf16
  return pk2(h2f((u16)(w & 0xFFFF)), h2f((u16)(w >> 16)));
}
__device__ __forceinline__ float fdot2u(u32 a, u32 b, float c) {
  union { u32 u; h16x2 h; } ua, ub; ua.u = a; ub.u = b;
#if __has_builtin(__builtin_amdgcn_fdot2)
  return __builtin_amdgcn_fdot2(ua.h, ub.h, c, false);
#else
  return c + (float)ua.h.x * (float)ub.h.x + (float)ua.h.y * (float)ub.h.y;
#endif
}

// ---------------------------------------------------------------------------
// Kernel 0: z<3: transpose+cast Wq/Wk/Wv (f32 [256][256] -> bf16 WT [n][k]).
//           z==3 (block 0,0): Wg2^T bf16 padded [32][40]  AND  Wg1^T bf16
//           padded [32][256] (rows 24..31 zero).
// ---------------------------------------------------------------------------
__global__ __launch_bounds__(256) void prep_transpose(
    const float* __restrict__ Wq, const float* __restrict__ Wk, const float* __restrict__ Wv,
    const float* __restrict__ Wg2, const float* __restrict__ Wg1,
    u16* __restrict__ WTq, u16* __restrict__ WTk, u16* __restrict__ WTv,
    u16* __restrict__ wg2bf, u16* __restrict__ wg1T)
{
  int z = blockIdx.z, bx = blockIdx.x, by = blockIdx.y;
  int x = threadIdx.x, y = threadIdx.y;  // 32 x 8
  if (z == 3) {
    if (bx || by) return;
    int t = y * 32 + x;
    for (int i = t; i < 1280; i += 256) {
      int j = i / 40, k = i % 40;
      float v = (j < 24 && k < 24) ? Wg2[(size_t)k * 24 + j] : 0.f;
      wg2bf[i] = f2bf(v);
    }
    // Wg1^T: wg1T[j*256 + e] = Wg1[e*24 + j] (j<24), zero rows j>=24
    for (int j = 0; j < 24; j++)
      wg1T[(size_t)j * 256 + t] = f2bf(Wg1[(size_t)t * 24 + j]);
    for (int j = 24; j < 32; j++)
      wg1T[(size_t)j * 256 + t] = 0;
    return;
  }
  __shared__ u16 tile[32][33];
  const float* W  = (z == 0) ? Wq : (z == 1) ? Wk : Wv;
  u16*         WT = (z == 0) ? WTq : (z == 1) ? WTk : WTv;
  for (int yy = y; yy < 32; yy += 8)
    tile[yy][x] = f2bf(W[(size_t)(by * 32 + yy) * 256 + bx * 32 + x]);
  __syncthreads();
  for (int yy = y; yy < 32; yy += 8)
    WT[(size_t)(bx * 32 + yy) * 256 + by * 32 + x] = tile[x][yy];
}

// ---------------------------------------------------------------------------
// Kernel 1: q/k/v projections. grid (64 m-tiles, 2 n-blks, 3 matrices).
// Y[8192,256] = X @ W + b  (f16 out).
// ---------------------------------------------------------------------------
__global__ __launch_bounds__(256) void gemm_qkv(
    const float* __restrict__ Xq, const float* __restrict__ Xk, const float* __restrict__ Xv,
    const u16* __restrict__ WTq, const u16* __restrict__ WTk, const u16* __restrict__ WTv,
    const float* __restrict__ bq, const float* __restrict__ bk, const float* __restrict__ bv,
    u16* __restrict__ Oq, u16* __restrict__ Ok, u16* __restrict__ Ov)
{
  int z = blockIdx.z;
  const float* X    = (z == 0) ? Xq : (z == 1) ? Xk : Xv;
  const u16*   WT   = (z == 0) ? WTq : (z == 1) ? WTk : WTv;
  const float* bias = (z == 0) ? bq : (z == 1) ? bk : bv;
  u16*         O    = (z == 0) ? Oq : (z == 1) ? Ok : Ov;

  int m0 = blockIdx.x * 128;
  int n0 = blockIdx.y * 128;
  int t = threadIdx.x;
  int lane = t & 63, wid = t >> 6;
  int wr = wid >> 1, wc = wid & 1;
  int fr = lane & 15, fg = lane >> 4;
  int sr = t >> 1;
  int sc = (t & 1) * 16;

  __shared__ __align__(16) u16 la[128 * LDT];
  __shared__ __align__(16) u16 lb[128 * LDT];

  f32x4 acc[4][4];
#pragma unroll
  for (int i = 0; i < 4; i++)
#pragma unroll
    for (int j = 0; j < 4; j++) acc[i][j] = (f32x4){0.f, 0.f, 0.f, 0.f};

  for (int kt = 0; kt < 256; kt += 32) {
    const float4* ga = (const float4*)(X + (size_t)(m0 + sr) * 256 + kt + sc);
    float4 a0 = ga[0], a1 = ga[1], a2 = ga[2], a3 = ga[3];
    const uint4* gb = (const uint4*)(WT + (size_t)(n0 + sr) * 256 + kt + sc);
    uint4 b0 = gb[0], b1 = gb[1];

    uint4 wa0, wa1;
    wa0.x = pk2(a0.x, a0.y); wa0.y = pk2(a0.z, a0.w);
    wa0.z = pk2(a1.x, a1.y); wa0.w = pk2(a1.z, a1.w);
    wa1.x = pk2(a2.x, a2.y); wa1.y = pk2(a2.z, a2.w);
    wa1.z = pk2(a3.x, a3.y); wa1.w = pk2(a3.z, a3.w);

    __syncthreads();
    *(uint4*)&la[sr * LDT + sc]     = wa0;
    *(uint4*)&la[sr * LDT + sc + 8] = wa1;
    *(uint4*)&lb[sr * LDT + sc]     = b0;
    *(uint4*)&lb[sr * LDT + sc + 8] = b1;
    __syncthreads();

    bf16x8 af[4], bfr[4];
#pragma unroll
    for (int s = 0; s < 4; s++)
      af[s] = *(const bf16x8*)&la[(wr * 64 + s * 16 + fr) * LDT + fg * 8];
#pragma unroll
    for (int s = 0; s < 4; s++)
      bfr[s] = *(const bf16x8*)&lb[(wc * 64 + s * 16 + fr) * LDT + fg * 8];
#pragma unroll
    for (int i = 0; i < 4; i++)
#pragma unroll
      for (int j = 0; j < 4; j++)
        acc[i][j] = __builtin_amdgcn_mfma_f32_16x16x32_bf16(af[i], bfr[j], acc[i][j], 0, 0, 0);
  }

#pragma unroll
  for (int i = 0; i < 4; i++) {
    int rowb = m0 + wr * 64 + i * 16 + fg * 4;
#pragma unroll
    for (int j = 0; j < 4; j++) {
      int col = n0 + wc * 64 + j * 16 + fr;
      float bb = bias[col];
#pragma unroll
      for (int r = 0; r < 4; r++)
        O[(size_t)(rowb + r) * 256 + col] = f2h(acc[i][j][r] + bb);
    }
  }
}

// ---------------------------------------------------------------------------
// Kernel 1b: kg1 = kbuf @ Wg1 (f16 out, stride 32); qadj = qbuf @ Wg1 - bg1.
// grid (64 m-tiles, 2). A = f16 workspace rows converted to bf16 in staging.
// ---------------------------------------------------------------------------
__global__ __launch_bounds__(256) void gemm_g1(
    const u16* __restrict__ kbuf, const u16* __restrict__ qbuf,
    const u16* __restrict__ wg1T, const float* __restrict__ bg1,
    u16* __restrict__ kg1, u16* __restrict__ qadj)
{
  int z = blockIdx.y;                      // 0: kg1, 1: qadj
  const u16* X = (z == 0) ? kbuf : qbuf;
  u16*       O = (z == 0) ? kg1 : qadj;

  int m0 = blockIdx.x * 128;
  int t = threadIdx.x;
  int lane = t & 63, wid = t >> 6;
  int fr = lane & 15, fg = lane >> 4;
  int sr = t >> 1;
  int sc = (t & 1) * 16;

  __shared__ __align__(16) u16 la[128 * LDT];
  __shared__ __align__(16) u16 lb[32 * LDT];

  f32x4 acc[2][2];
#pragma unroll
  for (int i = 0; i < 2; i++)
#pragma unroll
    for (int j = 0; j < 2; j++) acc[i][j] = (f32x4){0.f, 0.f, 0.f, 0.f};

  for (int kt = 0; kt < 256; kt += 32) {
    const uint4* ga = (const uint4*)(X + (size_t)(m0 + sr) * 256 + kt + sc);
    uint4 a0 = ga[0], a1 = ga[1];             // 16 f16
    uint4 b0, b1;
    if (t < 64) {
      const uint4* gb = (const uint4*)(wg1T + (size_t)sr * 256 + kt + sc);
      b0 = gb[0]; b1 = gb[1];
    }
    uint4 wa0, wa1;
    wa0.x = h2bf2(a0.x); wa0.y = h2bf2(a0.y);
    wa0.z = h2bf2(a0.z); wa0.w = h2bf2(a0.w);
    wa1.x = h2bf2(a1.x); wa1.y = h2bf2(a1.y);
    wa1.z = h2bf2(a1.z); wa1.w = h2bf2(a1.w);

    __syncthreads();
    *(uint4*)&la[sr * LDT + sc]     = wa0;
    *(uint4*)&la[sr * LDT + sc + 8] = wa1;
    if (t < 64) {
      *(uint4*)&lb[sr * LDT + sc]     = b0;
      *(uint4*)&lb[sr * LDT + sc + 8] = b1;
    }
    __syncthreads();

    bf16x8 af[2], bfr[2];
#pragma unroll
    for (int s = 0; s < 2; s++)
      af[s] = *(const bf16x8*)&la[(wid * 32 + s * 16 + fr) * LDT + fg * 8];
#pragma unroll
    for (int s = 0; s < 2; s++)
      bfr[s] = *(const bf16x8*)&lb[(s * 16 + fr) * LDT + fg * 8];
#pragma unroll
    for (int i = 0; i < 2; i++)
#pragma unroll
      for (int j = 0; j < 2; j++)
        acc[i][j] = __builtin_amdgcn_mfma_f32_16x16x32_bf16(af[i], bfr[j], acc[i][j], 0, 0, 0);
  }

#pragma unroll
  for (int i = 0; i < 2; i++) {
    int rowb = m0 + wid * 32 + i * 16 + fg * 4;
#pragma unroll
    for (int j = 0; j < 2; j++) {
      int col = j * 16 + fr;
      if (col < 24) {
        float sub = (z == 1) ? bg1[col] : 0.f;
#pragma unroll
        for (int r = 0; r < 4; r++)
          O[(size_t)(rowb + r) * 32 + col] = f2h(acc[i][j][r] - sub);
      }
    }
  }
}

// ---------------------------------------------------------------------------
// Kernel 2: logits + softmax -> att f16 [P][32 n][8 h], normalized.
// Gathers ONLY kbuf (4MB) + kg1 (0.5MB). All streaming accesses are
// non-temporal to protect gather-set L2 residency.
// ---------------------------------------------------------------------------
__global__ __launch_bounds__(256) void attn_logits(
    const u16* __restrict__ qb, const u16* __restrict__ kb,
    const u16* __restrict__ kg1g, const u16* __restrict__ qadjg,
    const int* __restrict__ ip, const float* __restrict__ raw,
    const float* __restrict__ rpe, const u16* __restrict__ wg2bf,
    const float* __restrict__ bg2g, u16* __restrict__ attg)
{
  int p = blockIdx.x, t = threadIdx.x;
  int lane = t & 63, w = t >> 6;
  int fr = lane & 15, fg = lane >> 4;
  int n = t >> 3, h = t & 7;

  __shared__ __align__(16) u16   wg2_s[32 * 40];   // bf16 Wg2^T padded
  __shared__ __align__(16) u16   kg1_s[32 * 40];   // f16 gathered kg1 rows
  __shared__              float qadj_s[24];
  __shared__              float bg2_s[24];
  __shared__              float sh_s[96];
  __shared__              float g_s[32 * 33];
  __shared__              float ev_s[256];
  __shared__              float is_s[8];

  int myidx = ip[(size_t)p * 32 + n];
  float rw = __builtin_nontemporal_load(raw + (size_t)p * 256 + t);

  // ---- Phase A: staging
  if ((t & 7) < 4)
    *(uint4*)&kg1_s[n * 40 + (t & 7) * 8] =
        *(const uint4*)(kg1g + (size_t)myidx * 32 + (t & 7) * 8);
  if (t < 160) *(uint4*)&wg2_s[t * 8] = ((const uint4*)wg2bf)[t];
  else if (t < 192) {
    int nn = t - 160;
    float x  = __builtin_nontemporal_load(rpe + (size_t)p * 96 + nn * 3 + 0);
    float y  = __builtin_nontemporal_load(rpe + (size_t)p * 96 + nn * 3 + 1);
    float z  = __builtin_nontemporal_load(rpe + (size_t)p * 96 + nn * 3 + 2);
    float rl = sqrtf(x * x + y * y + z * z);
    float inv = 1.f / fmaxf(rl, 1e-12f);
    float tt2 = fminf(fmaxf((rl - 0.001f) * 250.f, 0.f), 1.f);
    float cut = 0.5f * (1.f - cosf(tt2 * 3.14159265358979f));
    float s3c = 1.7320508075688772f * inv * cut;
    sh_s[nn * 3 + 0] = x * s3c; sh_s[nn * 3 + 1] = y * s3c; sh_s[nn * 3 + 2] = z * s3c;
  }
  else if (t >= 192 && t < 216)
    qadj_s[t - 192] = h2f(__builtin_nontemporal_load(qadjg + (size_t)p * 32 + (t - 192)));
  else if (t >= 224 && t < 248) bg2_s[t - 224] = bg2g[t - 224];
  __syncthreads();

  // ---- Phase B: MLP g = relu(kg1_g - qadj) @ Wg2 + bg2 (1 MFMA per wave)
  {
    int mt = w & 1, jt = w >> 1;
    union { u32 u[4]; bf16x8 v; } a;
    if (fg < 3) {
      const u16*   kr = &kg1_s[(mt * 16 + fr) * 40 + fg * 8];
      const float* qr = &qadj_s[fg * 8];
      float x0 = fmaxf(h2f(kr[0]) - qr[0], 0.f), x1 = fmaxf(h2f(kr[1]) - qr[1], 0.f);
      float x2 = fmaxf(h2f(kr[2]) - qr[2], 0.f), x3 = fmaxf(h2f(kr[3]) - qr[3], 0.f);
      float x4 = fmaxf(h2f(kr[4]) - qr[4], 0.f), x5 = fmaxf(h2f(kr[5]) - qr[5], 0.f);
      float x6 = fmaxf(h2f(kr[6]) - qr[6], 0.f), x7 = fmaxf(h2f(kr[7]) - qr[7], 0.f);
      a.u[0] = pk2(x0, x1); a.u[1] = pk2(x2, x3);
      a.u[2] = pk2(x4, x5); a.u[3] = pk2(x6, x7);
    } else {
      a.u[0] = a.u[1] = a.u[2] = a.u[3] = 0;
    }
    bf16x8 b = *(const bf16x8*)&wg2_s[(jt * 16 + fr) * 40 + fg * 8];
    f32x4 g = (f32x4){0.f, 0.f, 0.f, 0.f};
    g = __builtin_amdgcn_mfma_f32_16x16x32_bf16(a.v, b, g, 0, 0, 0);
    int j = jt * 16 + fr;
    float bb = (j < 24) ? bg2_s[j] : 0.f;
    int e0 = mt * 16 + fg * 4;
#pragma unroll
    for (int r = 0; r < 4; r++)
      g_s[(e0 + r) * 33 + j] = g[r] + bb;
  }
  __syncthreads();

  // ---- Phase C: dot (k gather cached; q non-temporal) + pos + raw -> e-values
  float ev;
  {
    const uint4*  kr = (const uint4*)(kb + (size_t)myidx * 256 + h * 32);
    const u32x4*  qr = (const u32x4*)(qb + (size_t)p * 256 + h * 32);
    float dot = 0.f;
#pragma unroll
    for (int c = 0; c < 4; c++) {
      uint4 kw = kr[c];
      u32x4 qw = __builtin_nontemporal_load(qr + c);
      dot = fdot2u(kw.x, qw[0], dot);
      dot = fdot2u(kw.y, qw[1], dot);
      dot = fdot2u(kw.z, qw[2], dot);
      dot = fdot2u(kw.w, qw[3], dot);
    }
    float pos = g_s[n * 33 + h * 3 + 0] * sh_s[n * 3 + 0]
              + g_s[n * 33 + h * 3 + 1] * sh_s[n * 3 + 1]
              + g_s[n * 33 + h * 3 + 2] * sh_s[n * 3 + 2];
    ev = __expf((dot + pos + rw) * 0.17677669529663687f);
    ev_s[t] = ev;
  }
  __syncthreads();

  // ---- Phase D: denominators (wave 0)
  if (w == 0) {
    int hh = lane & 7, g4 = lane >> 3;
    float s = ev_s[(g4 * 4 + 0) * 8 + hh] + ev_s[(g4 * 4 + 1) * 8 + hh]
            + ev_s[(g4 * 4 + 2) * 8 + hh] + ev_s[(g4 * 4 + 3) * 8 + hh];
    s += __shfl_xor(s, 8, 64);
    s += __shfl_xor(s, 16, 64);
    s += __shfl_xor(s, 32, 64);
    if (lane < 8) is_s[hh] = 1.f / s;
  }
  __syncthreads();

  // ---- Phase E: normalized att f16 out (non-temporal)
  __builtin_nontemporal_store(f2h(ev * is_s[h]), attg + (size_t)p * 256 + t);
}

// ---------------------------------------------------------------------------
// Kernel 3: PV. 4 points/block, 1 wave/point (wave-private, no barrier).
// Gathers ONLY vbuf (4MB). att read + out write non-temporal.
// ---------------------------------------------------------------------------
__global__ __launch_bounds__(256) void attn_pv(
    const u16* __restrict__ vb, const u16* __restrict__ attg,
    const int* __restrict__ ip, float* __restrict__ out)
{
  int t = threadIdx.x, wid = t >> 6, l = t & 63;
  int p = blockIdx.x * 4 + wid;
  __shared__ __align__(8) u16 att_s[4][256];
  __shared__ int idx_s[4][32];

  u32x2 aw = __builtin_nontemporal_load((const u32x2*)(attg + (size_t)p * 256 + l * 4));
  *(u32x2*)&att_s[wid][l * 4] = aw;
  if (l < 32) idx_s[wid][l] = ip[(size_t)p * 32 + l];

  int hh = l >> 3;
  float a0 = 0.f, a1 = 0.f, a2 = 0.f, a3 = 0.f;
#pragma unroll
  for (int n = 0; n < 32; n++) {
    float wt = h2f(att_s[wid][n * 8 + hh]);
    uint2 vv = *(const uint2*)(vb + (size_t)idx_s[wid][n] * 256 + l * 4);
    a0 += wt * h2f((u16)(vv.x & 0xFFFF));
    a1 += wt * h2f((u16)(vv.x >> 16));
    a2 += wt * h2f((u16)(vv.y & 0xFFFF));
    a3 += wt * h2f((u16)(vv.y >> 16));
  }
  f32x4v r; r[0] = a0; r[1] = a1; r[2] = a2; r[3] = a3;
  __builtin_nontemporal_store(r, (f32x4v*)(out + (size_t)p * 256 + l * 4));
}

// ---------------------------------------------------------------------------
extern "C" void kernel_launch(void* const* d_in, const int* in_sizes, int n_in,
                              void* d_out, int out_size, void* d_ws, size_t ws_size,
                              hipStream_t stream) {
  const float* query = (const float*)d_in[0];
  const float* key_x = (const float*)d_in[1];
  const float* value = (const float*)d_in[2];
  const int*   index_pair = (const int*)d_in[3];
  const float* raw  = (const float*)d_in[4];
  const float* rpe  = (const float*)d_in[5];
  const float* Wq = (const float*)d_in[6];
  const float* bq = (const float*)d_in[7];
  const float* Wk = (const float*)d_in[8];
  const float* bk = (const float*)d_in[9];
  const float* Wv = (const float*)d_in[10];
  const float* bv = (const float*)d_in[11];
  const float* Wg1 = (const float*)d_in[12];
  const float* bg1 = (const float*)d_in[13];
  const float* Wg2 = (const float*)d_in[14];
  const float* bg2 = (const float*)d_in[15];
  float* out = (float*)d_out;

  char* ws = (char*)d_ws;
  u16*   qbuf  = (u16*)(ws);                           // 4MB  [8192][256] f16
  u16*   kbuf  = (u16*)(ws + (4u << 20));              // 4MB
  u16*   vbuf  = (u16*)(ws + (8u << 20));              // 4MB
  u16*   attb  = (u16*)(ws + (12u << 20));             // 4MB  [8192][32][8] f16
  u16*   qadj  = (u16*)(ws + (16u << 20));             // 512KB [8192][32] f16
  u16*   kg1   = (u16*)(ws + (16u << 20) + 524288);    // 512KB
  u16*   WTq   = (u16*)(ws + (17u << 20));             // 128KB each
  u16*   WTk   = WTq + 65536;
  u16*   WTv   = WTk + 65536;
  u16*   wg2bf = WTv + 65536;                          // [32][40] bf16
  u16*   wg1T  = wg2bf + 1280;                         // [32][256] bf16

  prep_transpose<<<dim3(8, 8, 4), dim3(32, 8, 1), 0, stream>>>(
      Wq, Wk, Wv, Wg2, Wg1, WTq, WTk, WTv, wg2bf, wg1T);
  gemm_qkv<<<dim3(64, 2, 3), 256, 0, stream>>>(
      query, key_x, value, WTq, WTk, WTv, bq, bk, bv, qbuf, kbuf, vbuf);
  gemm_g1<<<dim3(64, 2), 256, 0, stream>>>(
      kbuf, qbuf, wg1T, bg1, kg1, qadj);
  attn_logits<<<8192, 256, 0, stream>>>(
      qbuf, kbuf, kg1, qadj, index_pair, raw, rpe, wg2bf, bg2, attb);
  attn_pv<<<2048, 256, 0, stream>>>(
      vbuf, attb, index_pair, out);
}

// Round 9
// 64.142 us; speedup vs baseline: 1.4535x; 1.1333x over previous
//
#include <hip/hip_runtime.h>
#include <stdint.h>

typedef uint32_t u32;
typedef unsigned short u16;

#define LDT 40  // GEMM LDS row stride (elements)

typedef __bf16 bf16x8 __attribute__((ext_vector_type(8)));
typedef float  f32x4  __attribute__((ext_vector_type(4)));
typedef _Float16 h16x2 __attribute__((ext_vector_type(2)));
typedef u32    u32x4  __attribute__((ext_vector_type(4)));
typedef u32    u32x2  __attribute__((ext_vector_type(2)));
typedef float  f32x4v __attribute__((ext_vector_type(4)));

__device__ __forceinline__ float bf2f(u16 x) {
  union { float f; u32 u; } c; c.u = ((u32)x) << 16; return c.f;
}
__device__ __forceinline__ u16 f2bf(float f) {
  union { float f; u32 u; } c; c.f = f;
  u32 b = c.u;
  return (u16)((b + 0x7FFFu + ((b >> 16) & 1u)) >> 16);
}
__device__ __forceinline__ u32 pk2(float lo, float hi) {
  return (u32)f2bf(lo) | ((u32)f2bf(hi) << 16);
}
__device__ __forceinline__ u16 f2h(float f) {
  union { _Float16 h; u16 u; } c; c.h = (_Float16)f; return c.u;
}
__device__ __forceinline__ float h2f(u16 x) {
  union { _Float16 h; u16 u; } c; c.u = x; return (float)c.h;
}
__device__ __forceinline__ u32 h2bf2(u32 w) {  // 2 f16 -> 2 bf16
  return pk2(h2f((u16)(w & 0xFFFF)), h2f((u16)(w >> 16)));
}
__device__ __forceinline__ float fdot2u(u32 a, u32 b, float c) {
  union { u32 u; h16x2 h; } ua, ub; ua.u = a; ub.u = b;
#if __has_builtin(__builtin_amdgcn_fdot2)
  return __builtin_amdgcn_fdot2(ua.h, ub.h, c, false);
#else
  return c + (float)ua.h.x * (float)ub.h.x + (float)ua.h.y * (float)ub.h.y;
#endif
}

// ---------------------------------------------------------------------------
// Kernel 0: z<3: transpose+cast Wq/Wk/Wv (f32 [256][256] -> bf16 WT [n][k]).
//           z==3 (block 0,0): Wg2^T bf16 padded [32][40]  AND  Wg1^T bf16
//           padded [32][256] (rows 24..31 zero).
// ---------------------------------------------------------------------------
__global__ __launch_bounds__(256) void prep_transpose(
    const float* __restrict__ Wq, const float* __restrict__ Wk, const float* __restrict__ Wv,
    const float* __restrict__ Wg2, const float* __restrict__ Wg1,
    u16* __restrict__ WTq, u16* __restrict__ WTk, u16* __restrict__ WTv,
    u16* __restrict__ wg2bf, u16* __restrict__ wg1T)
{
  int z = blockIdx.z, bx = blockIdx.x, by = blockIdx.y;
  int x = threadIdx.x, y = threadIdx.y;  // 32 x 8
  if (z == 3) {
    if (bx || by) return;
    int t = y * 32 + x;
    for (int i = t; i < 1280; i += 256) {
      int j = i / 40, k = i % 40;
      float v = (j < 24 && k < 24) ? Wg2[(size_t)k * 24 + j] : 0.f;
      wg2bf[i] = f2bf(v);
    }
    for (int j = 0; j < 24; j++)
      wg1T[(size_t)j * 256 + t] = f2bf(Wg1[(size_t)t * 24 + j]);
    for (int j = 24; j < 32; j++)
      wg1T[(size_t)j * 256 + t] = 0;
    return;
  }
  __shared__ u16 tile[32][33];
  const float* W  = (z == 0) ? Wq : (z == 1) ? Wk : Wv;
  u16*         WT = (z == 0) ? WTq : (z == 1) ? WTk : WTv;
  for (int yy = y; yy < 32; yy += 8)
    tile[yy][x] = f2bf(W[(size_t)(by * 32 + yy) * 256 + bx * 32 + x]);
  __syncthreads();
  for (int yy = y; yy < 32; yy += 8)
    WT[(size_t)(bx * 32 + yy) * 256 + by * 32 + x] = tile[x][yy];
}

// ---------------------------------------------------------------------------
// Kernel 1: q/k/v projections. BM=64: grid (128 m-tiles, 2 n-blks, 3 mats)
// = 768 blocks (3/CU). Y[8192,256] = X @ W + b (f16 out).
// ---------------------------------------------------------------------------
__global__ __launch_bounds__(256) void gemm_qkv(
    const float* __restrict__ Xq, const float* __restrict__ Xk, const float* __restrict__ Xv,
    const u16* __restrict__ WTq, const u16* __restrict__ WTk, const u16* __restrict__ WTv,
    const float* __restrict__ bq, const float* __restrict__ bk, const float* __restrict__ bv,
    u16* __restrict__ Oq, u16* __restrict__ Ok, u16* __restrict__ Ov)
{
  int z = blockIdx.z;
  const float* X    = (z == 0) ? Xq : (z == 1) ? Xk : Xv;
  const u16*   WT   = (z == 0) ? WTq : (z == 1) ? WTk : WTv;
  const float* bias = (z == 0) ? bq : (z == 1) ? bk : bv;
  u16*         O    = (z == 0) ? Oq : (z == 1) ? Ok : Ov;

  int m0 = blockIdx.x * 64;
  int n0 = blockIdx.y * 128;
  int t = threadIdx.x;
  int lane = t & 63, wid = t >> 6;
  int wr = wid >> 1, wc = wid & 1;
  int fr = lane & 15, fg = lane >> 4;
  int sra = t >> 2;             // 0..63  (A rows)
  int sca = (t & 3) * 8;        // 0,8,16,24
  int srb = t >> 1;             // 0..127 (B rows)
  int scb = (t & 1) * 16;

  __shared__ __align__(16) u16 la[64 * LDT];
  __shared__ __align__(16) u16 lb[128 * LDT];

  f32x4 acc[2][4];
#pragma unroll
  for (int i = 0; i < 2; i++)
#pragma unroll
    for (int j = 0; j < 4; j++) acc[i][j] = (f32x4){0.f, 0.f, 0.f, 0.f};

  for (int kt = 0; kt < 256; kt += 32) {
    const float4* ga = (const float4*)(X + (size_t)(m0 + sra) * 256 + kt + sca);
    float4 a0 = ga[0], a1 = ga[1];
    const uint4* gb = (const uint4*)(WT + (size_t)(n0 + srb) * 256 + kt + scb);
    uint4 b0 = gb[0], b1 = gb[1];

    uint4 wa;
    wa.x = pk2(a0.x, a0.y); wa.y = pk2(a0.z, a0.w);
    wa.z = pk2(a1.x, a1.y); wa.w = pk2(a1.z, a1.w);

    __syncthreads();
    *(uint4*)&la[sra * LDT + sca]     = wa;
    *(uint4*)&lb[srb * LDT + scb]     = b0;
    *(uint4*)&lb[srb * LDT + scb + 8] = b1;
    __syncthreads();

    bf16x8 af[2], bfr[4];
#pragma unroll
    for (int s = 0; s < 2; s++)
      af[s] = *(const bf16x8*)&la[(wr * 32 + s * 16 + fr) * LDT + fg * 8];
#pragma unroll
    for (int j = 0; j < 4; j++)
      bfr[j] = *(const bf16x8*)&lb[(wc * 64 + j * 16 + fr) * LDT + fg * 8];
#pragma unroll
    for (int i = 0; i < 2; i++)
#pragma unroll
      for (int j = 0; j < 4; j++)
        acc[i][j] = __builtin_amdgcn_mfma_f32_16x16x32_bf16(af[i], bfr[j], acc[i][j], 0, 0, 0);
  }

#pragma unroll
  for (int i = 0; i < 2; i++) {
    int rowb = m0 + wr * 32 + i * 16 + fg * 4;
#pragma unroll
    for (int j = 0; j < 4; j++) {
      int col = n0 + wc * 64 + j * 16 + fr;
      float bb = bias[col];
#pragma unroll
      for (int r = 0; r < 4; r++)
        O[(size_t)(rowb + r) * 256 + col] = f2h(acc[i][j][r] + bb);
    }
  }
}

// ---------------------------------------------------------------------------
// Kernel 1b: kg1 = kbuf @ Wg1 (f16 out, stride 32); qadj = qbuf @ Wg1 - bg1.
// ---------------------------------------------------------------------------
__global__ __launch_bounds__(256) void gemm_g1(
    const u16* __restrict__ kbuf, const u16* __restrict__ qbuf,
    const u16* __restrict__ wg1T, const float* __restrict__ bg1,
    u16* __restrict__ kg1, u16* __restrict__ qadj)
{
  int z = blockIdx.y;                      // 0: kg1, 1: qadj
  const u16* X = (z == 0) ? kbuf : qbuf;
  u16*       O = (z == 0) ? kg1 : qadj;

  int m0 = blockIdx.x * 128;
  int t = threadIdx.x;
  int lane = t & 63, wid = t >> 6;
  int fr = lane & 15, fg = lane >> 4;
  int sr = t >> 1;
  int sc = (t & 1) * 16;

  __shared__ __align__(16) u16 la[128 * LDT];
  __shared__ __align__(16) u16 lb[32 * LDT];

  f32x4 acc[2][2];
#pragma unroll
  for (int i = 0; i < 2; i++)
#pragma unroll
    for (int j = 0; j < 2; j++) acc[i][j] = (f32x4){0.f, 0.f, 0.f, 0.f};

  for (int kt = 0; kt < 256; kt += 32) {
    const uint4* ga = (const uint4*)(X + (size_t)(m0 + sr) * 256 + kt + sc);
    uint4 a0 = ga[0], a1 = ga[1];
    uint4 b0, b1;
    if (t < 64) {
      const uint4* gb = (const uint4*)(wg1T + (size_t)sr * 256 + kt + sc);
      b0 = gb[0]; b1 = gb[1];
    }
    uint4 wa0, wa1;
    wa0.x = h2bf2(a0.x); wa0.y = h2bf2(a0.y);
    wa0.z = h2bf2(a0.z); wa0.w = h2bf2(a0.w);
    wa1.x = h2bf2(a1.x); wa1.y = h2bf2(a1.y);
    wa1.z = h2bf2(a1.z); wa1.w = h2bf2(a1.w);

    __syncthreads();
    *(uint4*)&la[sr * LDT + sc]     = wa0;
    *(uint4*)&la[sr * LDT + sc + 8] = wa1;
    if (t < 64) {
      *(uint4*)&lb[sr * LDT + sc]     = b0;
      *(uint4*)&lb[sr * LDT + sc + 8] = b1;
    }
    __syncthreads();

    bf16x8 af[2], bfr[2];
#pragma unroll
    for (int s = 0; s < 2; s++)
      af[s] = *(const bf16x8*)&la[(wid * 32 + s * 16 + fr) * LDT + fg * 8];
#pragma unroll
    for (int s = 0; s < 2; s++)
      bfr[s] = *(const bf16x8*)&lb[(s * 16 + fr) * LDT + fg * 8];
#pragma unroll
    for (int i = 0; i < 2; i++)
#pragma unroll
      for (int j = 0; j < 2; j++)
        acc[i][j] = __builtin_amdgcn_mfma_f32_16x16x32_bf16(af[i], bfr[j], acc[i][j], 0, 0, 0);
  }

#pragma unroll
  for (int i = 0; i < 2; i++) {
    int rowb = m0 + wid * 32 + i * 16 + fg * 4;
#pragma unroll
    for (int j = 0; j < 2; j++) {
      int col = j * 16 + fr;
      if (col < 24) {
        float sub = (z == 1) ? bg1[col] : 0.f;
#pragma unroll
        for (int r = 0; r < 4; r++)
          O[(size_t)(rowb + r) * 32 + col] = f2h(acc[i][j][r] - sub);
      }
    }
  }
}

// ---------------------------------------------------------------------------
// Kernel 2: logits + softmax -> att f16 [P][32 n][8 h], normalized.
// k-row gather + q/raw streams PREFETCHED into registers at kernel start;
// Phase C (dot) runs entirely out of registers.
// ---------------------------------------------------------------------------
__global__ __launch_bounds__(256) void attn_logits(
    const u16* __restrict__ qb, const u16* __restrict__ kb,
    const u16* __restrict__ kg1g, const u16* __restrict__ qadjg,
    const int* __restrict__ ip, const float* __restrict__ raw,
    const float* __restrict__ rpe, const u16* __restrict__ wg2bf,
    const float* __restrict__ bg2g, u16* __restrict__ attg)
{
  int p = blockIdx.x, t = threadIdx.x;
  int lane = t & 63, w = t >> 6;
  int fr = lane & 15, fg = lane >> 4;
  int n = t >> 3, h = t & 7;

  __shared__ __align__(16) u16   wg2_s[32 * 40];   // bf16 Wg2^T padded
  __shared__ __align__(16) u16   kg1_s[32 * 40];   // f16 gathered kg1 rows
  __shared__              float qadj_s[24];
  __shared__              float bg2_s[24];
  __shared__              float sh_s[96];
  __shared__              float g_s[32 * 33];
  __shared__              float ev_s[256];
  __shared__              float is_s[8];

  int myidx = ip[(size_t)p * 32 + n];

  // ---- early-issue LDS-destined loads
  uint4 kg1w = {0, 0, 0, 0};
  if ((t & 7) < 4) kg1w = *(const uint4*)(kg1g + (size_t)myidx * 32 + (t & 7) * 8);
  uint4 wgw = {0, 0, 0, 0};
  if (t < 160) wgw = ((const uint4*)wg2bf)[t];
  float rx = 0.f, ry = 0.f, rz = 0.f;
  if (t >= 160 && t < 192) {
    int nn = t - 160;
    rx = __builtin_nontemporal_load(rpe + (size_t)p * 96 + nn * 3 + 0);
    ry = __builtin_nontemporal_load(rpe + (size_t)p * 96 + nn * 3 + 1);
    rz = __builtin_nontemporal_load(rpe + (size_t)p * 96 + nn * 3 + 2);
  }
  u16 qaw = 0;
  if (t >= 192 && t < 216)
    qaw = __builtin_nontemporal_load(qadjg + (size_t)p * 32 + (t - 192));
  float bgw = 0.f;
  if (t >= 224 && t < 248) bgw = bg2g[t - 224];

  // ---- prefetch: gathered k row (64B) + streamed q row slice + raw, -> regs
  const uint4* kr = (const uint4*)(kb + (size_t)myidx * 256 + h * 32);
  uint4 k0 = kr[0], k1 = kr[1], k2 = kr[2], k3 = kr[3];
  const u32x4* qr = (const u32x4*)(qb + (size_t)p * 256 + h * 32);
  u32x4 q0 = __builtin_nontemporal_load(qr + 0);
  u32x4 q1 = __builtin_nontemporal_load(qr + 1);
  u32x4 q2 = __builtin_nontemporal_load(qr + 2);
  u32x4 q3 = __builtin_nontemporal_load(qr + 3);
  float rw = __builtin_nontemporal_load(raw + (size_t)p * 256 + t);

  // ---- Phase A: LDS stores + sh
  if ((t & 7) < 4) *(uint4*)&kg1_s[n * 40 + (t & 7) * 8] = kg1w;
  if (t < 160) *(uint4*)&wg2_s[t * 8] = wgw;
  else if (t < 192) {
    int nn = t - 160;
    float rl = sqrtf(rx * rx + ry * ry + rz * rz);
    float inv = 1.f / fmaxf(rl, 1e-12f);
    float tt2 = fminf(fmaxf((rl - 0.001f) * 250.f, 0.f), 1.f);
    float cut = 0.5f * (1.f - cosf(tt2 * 3.14159265358979f));
    float s3c = 1.7320508075688772f * inv * cut;
    sh_s[nn * 3 + 0] = rx * s3c; sh_s[nn * 3 + 1] = ry * s3c; sh_s[nn * 3 + 2] = rz * s3c;
  }
  else if (t >= 192 && t < 216) qadj_s[t - 192] = h2f(qaw);
  else if (t >= 224 && t < 248) bg2_s[t - 224] = bgw;
  __syncthreads();

  // ---- Phase B: MLP g = relu(kg1_g - qadj) @ Wg2 + bg2 (1 MFMA per wave)
  {
    int mt = w & 1, jt = w >> 1;
    union { u32 u[4]; bf16x8 v; } a;
    if (fg < 3) {
      const u16*   krow = &kg1_s[(mt * 16 + fr) * 40 + fg * 8];
      const float* qrow = &qadj_s[fg * 8];
      float x0 = fmaxf(h2f(krow[0]) - qrow[0], 0.f), x1 = fmaxf(h2f(krow[1]) - qrow[1], 0.f);
      float x2 = fmaxf(h2f(krow[2]) - qrow[2], 0.f), x3 = fmaxf(h2f(krow[3]) - qrow[3], 0.f);
      float x4 = fmaxf(h2f(krow[4]) - qrow[4], 0.f), x5 = fmaxf(h2f(krow[5]) - qrow[5], 0.f);
      float x6 = fmaxf(h2f(krow[6]) - qrow[6], 0.f), x7 = fmaxf(h2f(krow[7]) - qrow[7], 0.f);
      a.u[0] = pk2(x0, x1); a.u[1] = pk2(x2, x3);
      a.u[2] = pk2(x4, x5); a.u[3] = pk2(x6, x7);
    } else {
      a.u[0] = a.u[1] = a.u[2] = a.u[3] = 0;
    }
    bf16x8 b = *(const bf16x8*)&wg2_s[(jt * 16 + fr) * 40 + fg * 8];
    f32x4 g = (f32x4){0.f, 0.f, 0.f, 0.f};
    g = __builtin_amdgcn_mfma_f32_16x16x32_bf16(a.v, b, g, 0, 0, 0);
    int j = jt * 16 + fr;
    float bb = (j < 24) ? bg2_s[j] : 0.f;
    int e0 = mt * 16 + fg * 4;
#pragma unroll
    for (int r = 0; r < 4; r++)
      g_s[(e0 + r) * 33 + j] = g[r] + bb;
  }
  __syncthreads();

  // ---- Phase C: dot from REGISTERS + pos + raw -> e-values
  float ev;
  {
    float dot = 0.f;
    dot = fdot2u(k0.x, q0[0], dot); dot = fdot2u(k0.y, q0[1], dot);
    dot = fdot2u(k0.z, q0[2], dot); dot = fdot2u(k0.w, q0[3], dot);
    dot = fdot2u(k1.x, q1[0], dot); dot = fdot2u(k1.y, q1[1], dot);
    dot = fdot2u(k1.z, q1[2], dot); dot = fdot2u(k1.w, q1[3], dot);
    dot = fdot2u(k2.x, q2[0], dot); dot = fdot2u(k2.y, q2[1], dot);
    dot = fdot2u(k2.z, q2[2], dot); dot = fdot2u(k2.w, q2[3], dot);
    dot = fdot2u(k3.x, q3[0], dot); dot = fdot2u(k3.y, q3[1], dot);
    dot = fdot2u(k3.z, q3[2], dot); dot = fdot2u(k3.w, q3[3], dot);
    float pos = g_s[n * 33 + h * 3 + 0] * sh_s[n * 3 + 0]
              + g_s[n * 33 + h * 3 + 1] * sh_s[n * 3 + 1]
              + g_s[n * 33 + h * 3 + 2] * sh_s[n * 3 + 2];
    ev = __expf((dot + pos + rw) * 0.17677669529663687f);
    ev_s[t] = ev;
  }
  __syncthreads();

  // ---- Phase D: denominators (wave 0)
  if (w == 0) {
    int hh = lane & 7, g4 = lane >> 3;
    float s = ev_s[(g4 * 4 + 0) * 8 + hh] + ev_s[(g4 * 4 + 1) * 8 + hh]
            + ev_s[(g4 * 4 + 2) * 8 + hh] + ev_s[(g4 * 4 + 3) * 8 + hh];
    s += __shfl_xor(s, 8, 64);
    s += __shfl_xor(s, 16, 64);
    s += __shfl_xor(s, 32, 64);
    if (lane < 8) is_s[hh] = 1.f / s;
  }
  __syncthreads();

  // ---- Phase E: normalized att f16 out (non-temporal)
  __builtin_nontemporal_store(f2h(ev * is_s[h]), attg + (size_t)p * 256 + t);
}

// ---------------------------------------------------------------------------
// Kernel 3: PV. 4 points/block, 1 wave/point (wave-private, no barrier).
// Gathers ONLY vbuf (4MB). att read + out write non-temporal.
// ---------------------------------------------------------------------------
__global__ __launch_bounds__(256) void attn_pv(
    const u16* __restrict__ vb, const u16* __restrict__ attg,
    const int* __restrict__ ip, float* __restrict__ out)
{
  int t = threadIdx.x, wid = t >> 6, l = t & 63;
  int p = blockIdx.x * 4 + wid;
  __shared__ __align__(8) u16 att_s[4][256];
  __shared__ int idx_s[4][32];

  u32x2 aw = __builtin_nontemporal_load((const u32x2*)(attg + (size_t)p * 256 + l * 4));
  *(u32x2*)&att_s[wid][l * 4] = aw;
  if (l < 32) idx_s[wid][l] = ip[(size_t)p * 32 + l];

  int hh = l >> 3;
  float a0 = 0.f, a1 = 0.f, a2 = 0.f, a3 = 0.f;
#pragma unroll
  for (int n = 0; n < 32; n++) {
    float wt = h2f(att_s[wid][n * 8 + hh]);
    uint2 vv = *(const uint2*)(vb + (size_t)idx_s[wid][n] * 256 + l * 4);
    a0 += wt * h2f((u16)(vv.x & 0xFFFF));
    a1 += wt * h2f((u16)(vv.x >> 16));
    a2 += wt * h2f((u16)(vv.y & 0xFFFF));
    a3 += wt * h2f((u16)(vv.y >> 16));
  }
  f32x4v r; r[0] = a0; r[1] = a1; r[2] = a2; r[3] = a3;
  __builtin_nontemporal_store(r, (f32x4v*)(out + (size_t)p * 256 + l * 4));
}

// ---------------------------------------------------------------------------
extern "C" void kernel_launch(void* const* d_in, const int* in_sizes, int n_in,
                              void* d_out, int out_size, void* d_ws, size_t ws_size,
                              hipStream_t stream) {
  const float* query = (const float*)d_in[0];
  const float* key_x = (const float*)d_in[1];
  const float* value = (const float*)d_in[2];
  const int*   index_pair = (const int*)d_in[3];
  const float* raw  = (const float*)d_in[4];
  const float* rpe  = (const float*)d_in[5];
  const float* Wq = (const float*)d_in[6];
  const float* bq = (const float*)d_in[7];
  const float* Wk = (const float*)d_in[8];
  const float* bk = (const float*)d_in[9];
  const float* Wv = (const float*)d_in[10];
  const float* bv = (const float*)d_in[11];
  const float* Wg1 = (const float*)d_in[12];
  const float* bg1 = (const float*)d_in[13];
  const float* Wg2 = (const float*)d_in[14];
  const float* bg2 = (const float*)d_in[15];
  float* out = (float*)d_out;

  char* ws = (char*)d_ws;
  u16*   qbuf  = (u16*)(ws);                           // 4MB  [8192][256] f16
  u16*   kbuf  = (u16*)(ws + (4u << 20));              // 4MB
  u16*   vbuf  = (u16*)(ws + (8u << 20));              // 4MB
  u16*   attb  = (u16*)(ws + (12u << 20));             // 4MB  [8192][32][8] f16
  u16*   qadj  = (u16*)(ws + (16u << 20));             // 512KB [8192][32] f16
  u16*   kg1   = (u16*)(ws + (16u << 20) + 524288);    // 512KB
  u16*   WTq   = (u16*)(ws + (17u << 20));             // 128KB each
  u16*   WTk   = WTq + 65536;
  u16*   WTv   = WTk + 65536;
  u16*   wg2bf = WTv + 65536;                          // [32][40] bf16
  u16*   wg1T  = wg2bf + 1280;                         // [32][256] bf16

  prep_transpose<<<dim3(8, 8, 4), dim3(32, 8, 1), 0, stream>>>(
      Wq, Wk, Wv, Wg2, Wg1, WTq, WTk, WTv, wg2bf, wg1T);
  gemm_qkv<<<dim3(128, 2, 3), 256, 0, stream>>>(
      query, key_x, value, WTq, WTk, WTv, bq, bk, bv, qbuf, kbuf, vbuf);
  gemm_g1<<<dim3(64, 2), 256, 0, stream>>>(
      kbuf, qbuf, wg1T, bg1, kg1, qadj);
  attn_logits<<<8192, 256, 0, stream>>>(
      qbuf, kbuf, kg1, qadj, index_pair, raw, rpe, wg2bf, bg2, attb);
  attn_pv<<<2048, 256, 0, stream>>>(
      vbuf, attb, index_pair, out);
}